// Round 1
// baseline (1722.737 us; speedup 1.0000x reference)
//
#include <hip/hip_runtime.h>
#include <hip/hip_bf16.h>

#define NN 50000
#define EE 500000
#define GG 64

__device__ __forceinline__ float wred_sum(float v) {
#pragma unroll
  for (int s = 32; s; s >>= 1) v += __shfl_xor(v, s, 64);
  return v;
}
__device__ __forceinline__ float wred_max(float v) {
#pragma unroll
  for (int s = 32; s; s >>= 1) v = fmaxf(v, __shfl_xor(v, s, 64));
  return v;
}

// ---- v = w_dst @ att_dst  (8 vectors of 128) ----
__global__ void v_kernel(const float* wdst, const float* adst, float* v) {
  int le = blockIdx.x;  // 0..7 = L*4+e
  int wid = threadIdx.x >> 6, lane = threadIdx.x & 63;  // 128 threads, 2 waves
  const float* W = wdst + (size_t)le * 128 * 128;
  const float* a = adst + le * 128;
  float a0 = a[lane], a1 = a[64 + lane];
  for (int k = wid; k < 128; k += 2) {
    float p = W[k * 128 + lane] * a0 + W[k * 128 + 64 + lane] * a1;
    p = wred_sum(p);
    if (lane == 0) v[le * 128 + k] = p;
  }
}

// ---- CSR build ----
__global__ void hist_kernel(const int* e0, const int* e1, const int* e2, const int* e3, int* deg) {
  int t = blockIdx.y;
  const int* dst = (t == 0 ? e0 : t == 1 ? e1 : t == 2 ? e2 : e3) + EE;
  for (int i = blockIdx.x * blockDim.x + threadIdx.x; i < EE; i += gridDim.x * blockDim.x)
    atomicAdd(&deg[t * NN + dst[i]], 1);
}

__global__ void scan_kernel(const int* deg, int* row_ptr, int* next) {
  int t = blockIdx.x;
  const int* d = deg + t * NN;
  int* rp = row_ptr + (size_t)t * (NN + 1);
  int* nx = next + t * NN;
  __shared__ int wsums[16];
  __shared__ int woff[16];
  __shared__ int carry;
  int tid = threadIdx.x, lane = tid & 63, wid = tid >> 6;
  if (tid == 0) { carry = 0; rp[0] = 0; }
  __syncthreads();
  for (int base = 0; base < NN; base += 1024) {
    int i = base + tid;
    int v = (i < NN) ? d[i] : 0;
    int orig = v;
#pragma unroll
    for (int s = 1; s < 64; s <<= 1) { int u = __shfl_up(v, s, 64); if (lane >= s) v += u; }
    if (lane == 63) wsums[wid] = v;
    __syncthreads();
    if (tid == 0) {
      int run = 0;
      for (int w = 0; w < 16; w++) { woff[w] = run; run += wsums[w]; }
      wsums[0] = run;
    }
    __syncthreads();
    int incl = carry + woff[wid] + v;
    if (i < NN) { rp[i + 1] = incl; nx[i] = incl - orig; }
    int ctot = wsums[0];
    __syncthreads();
    if (tid == 0) carry += ctot;
    __syncthreads();
  }
}

__global__ void scatter_kernel(const int* e0, const int* e1, const int* e2, const int* e3,
                               int* next, int* col) {
  int t = blockIdx.y;
  const int* ei = (t == 0 ? e0 : t == 1 ? e1 : t == 2 ? e2 : e3);
  const int* srcr = ei;
  const int* dstr = ei + EE;
  for (int i = blockIdx.x * blockDim.x + threadIdx.x; i < EE; i += gridDim.x * blockDim.x) {
    int dst = dstr[i];
    int pos = atomicAdd(&next[t * NN + dst], 1);
    col[(size_t)t * EE + pos] = srcr[i];
  }
}

// ---- GEMM h = X @ W (M=50000,K=128,N=128) + fused s = h @ att ----
#define GBM 128
#define GBK 16
__global__ __launch_bounds__(256) void gemm_hs_kernel(
    const float* XA, const float* WA, const float* attA, float* hA_, float* sA_,
    const float* XB, const float* WB, const float* attB, float* hB_, float* sB_) {
  const float *X, *W, *att;
  float *h, *s_;
  if (blockIdx.z == 0) { X = XA; W = WA; att = attA; h = hA_; s_ = sA_; }
  else                 { X = XB; W = WB; att = attB; h = hB_; s_ = sB_; }
  __shared__ float Xs[GBM][GBK + 1];
  __shared__ float Ws[GBK][128];
  __shared__ float s_lds[GBM];
  int tid = threadIdx.x;
  int tx = tid & 15, ty = tid >> 4;
  int row0 = blockIdx.x * GBM;
  float acc[8][8] = {};
  float attr[8];
#pragma unroll
  for (int j = 0; j < 8; j++) attr[j] = att[tx * 8 + j];
  for (int kt = 0; kt < 128; kt += GBK) {
#pragma unroll
    for (int u = 0; u < 2; u++) {
      int f4 = tid + u * 256;
      int r = f4 >> 2, kg = f4 & 3;
      int row = row0 + r; row = row < NN ? row : NN - 1;
      float4 xv = *(const float4*)(X + (size_t)row * 128 + kt + kg * 4);
      Xs[r][kg * 4 + 0] = xv.x; Xs[r][kg * 4 + 1] = xv.y;
      Xs[r][kg * 4 + 2] = xv.z; Xs[r][kg * 4 + 3] = xv.w;
    }
#pragma unroll
    for (int u = 0; u < 2; u++) {
      int f4 = tid + u * 256;
      int r = f4 >> 5, cg = f4 & 31;
      float4 wv = *(const float4*)(W + (size_t)(kt + r) * 128 + cg * 4);
      *(float4*)(&Ws[r][cg * 4]) = wv;
    }
    __syncthreads();
#pragma unroll
    for (int k = 0; k < GBK; k++) {
      float a[8], b[8];
#pragma unroll
      for (int i = 0; i < 8; i++) a[i] = Xs[ty * 8 + i][k];
      float4 b0 = *(float4*)(&Ws[k][tx * 8]);
      float4 b1 = *(float4*)(&Ws[k][tx * 8 + 4]);
      b[0] = b0.x; b[1] = b0.y; b[2] = b0.z; b[3] = b0.w;
      b[4] = b1.x; b[5] = b1.y; b[6] = b1.z; b[7] = b1.w;
#pragma unroll
      for (int i = 0; i < 8; i++)
#pragma unroll
        for (int j = 0; j < 8; j++) acc[i][j] += a[i] * b[j];
    }
    __syncthreads();
  }
  if (tid < GBM) s_lds[tid] = 0.f;
  __syncthreads();
#pragma unroll
  for (int i = 0; i < 8; i++) {
    int row = row0 + ty * 8 + i;
    float sp = 0.f;
#pragma unroll
    for (int j = 0; j < 8; j++) sp += acc[i][j] * attr[j];
    if (row < NN) {
      float4 o0 = make_float4(acc[i][0], acc[i][1], acc[i][2], acc[i][3]);
      float4 o1 = make_float4(acc[i][4], acc[i][5], acc[i][6], acc[i][7]);
      *(float4*)(h + (size_t)row * 128 + tx * 8) = o0;
      *(float4*)(h + (size_t)row * 128 + tx * 8 + 4) = o1;
    }
    atomicAdd(&s_lds[ty * 8 + i], sp);
  }
  __syncthreads();
  if (tid < GBM) {
    int row = row0 + tid;
    if (row < NN) s_[row] = s_lds[tid];
  }
}

// ---- per-dst-node GAT aggregation, two edge types fused, + inter-type mean + relu ----
__global__ __launch_bounds__(256) void agg_kernel(
    const float* xdst,
    const int* rpA, const int* colA, const float* hA_, const float* sA_, const float* vA, const float* bA,
    const int* rpB, const int* colB, const float* hB_, const float* sB_, const float* vB, const float* bB,
    float* Y) {
  int wid = threadIdx.x >> 6, lane = threadIdx.x & 63;
  int node = blockIdx.x * 4 + wid;
  if (node >= NN) return;
  float x0 = xdst[(size_t)node * 128 + lane];
  float x1 = xdst[(size_t)node * 128 + 64 + lane];
  float out0 = 0.f, out1 = 0.f;
  for (int t = 0; t < 2; t++) {
    const int* rp = t ? rpB : rpA;
    const int* col = t ? colB : colA;
    const float* h = t ? hB_ : hA_;
    const float* ss = t ? sB_ : sA_;
    const float* v = t ? vB : vA;
    const float* b = t ? bB : bA;
    float sd = wred_sum(x0 * v[lane] + x1 * v[64 + lane]);
    int start = rp[node], end = rp[node + 1];
    int deg = end - start;
    float m = -3.4e38f;
    for (int i = start + lane; i < end; i += 64) {
      float s = ss[col[i]] + sd;
      s = (s >= 0.f) ? s : 0.2f * s;
      m = fmaxf(m, s);
    }
    m = wred_max(m);
    float dsum = 0.f, a0 = 0.f, a1 = 0.f;
    for (int base = start; base < end; base += 64) {
      int i = base + lane;
      float ex = 0.f;
      int src = 0;
      if (i < end) {
        src = col[i];
        float s = ss[src] + sd;
        s = (s >= 0.f) ? s : 0.2f * s;
        ex = expf(s - m);
      }
      dsum += ex;
      int cc = min(64, end - base);
      for (int j = 0; j < cc; j++) {
        int sj = __shfl(src, j, 64);
        float exj = __shfl(ex, j, 64);
        const float* hr = h + (size_t)sj * 128;
        a0 += exj * hr[lane];
        a1 += exj * hr[64 + lane];
      }
    }
    float denom = wred_sum(dsum);
    float inv = (deg > 0) ? 1.0f / (denom * (float)deg) : 0.f;
    out0 += 0.5f * (a0 * inv + b[lane]);
    out1 += 0.5f * (a1 * inv + b[64 + lane]);
  }
  Y[(size_t)node * 128 + lane] = fmaxf(out0, 0.f);
  Y[(size_t)node * 128 + 64 + lane] = fmaxf(out1, 0.f);
}

// ---- mean pooling ----
__global__ void pool_kernel(const float* X, const int* batch, float* pooled, int* gcnt, int dimoff) {
  int wid = threadIdx.x >> 6, lane = threadIdx.x & 63;
  int node = blockIdx.x * 4 + wid;
  if (node >= NN) return;
  int g = batch[node];
  atomicAdd(&pooled[g * 256 + dimoff + lane], X[(size_t)node * 128 + lane]);
  atomicAdd(&pooled[g * 256 + dimoff + 64 + lane], X[(size_t)node * 128 + 64 + lane]);
  if (lane == 0) atomicAdd(&gcnt[g], 1);
}

// ---- final linear ----
__global__ void final_kernel(const float* pooled, const int* gA, const int* gB,
                             const float* wc, const float* bc, float* out) {
  int tid = blockIdx.x * blockDim.x + threadIdx.x;
  if (tid >= GG * 10) return;
  int g = tid / 10, o = tid % 10;
  float invA = 1.f / fmaxf((float)gA[g], 1.f);
  float invB = 1.f / fmaxf((float)gB[g], 1.f);
  float acc = bc[o];
  for (int k = 0; k < 256; k++) {
    float ge = pooled[g * 256 + k] * (k < 128 ? invA : invB);
    acc += ge * wc[k * 10 + o];
  }
  out[g * 10 + o] = acc;
}

extern "C" void kernel_launch(void* const* d_in, const int* in_sizes, int n_in,
                              void* d_out, int out_size, void* d_ws, size_t ws_size,
                              hipStream_t stream) {
  const float* xA = (const float*)d_in[0];
  const float* xB = (const float*)d_in[1];
  const int* ei0 = (const int*)d_in[2];
  const int* ei1 = (const int*)d_in[3];
  const int* ei2 = (const int*)d_in[4];
  const int* ei3 = (const int*)d_in[5];
  const int* batchA = (const int*)d_in[6];
  const int* batchB = (const int*)d_in[7];
  const float* wsrc = (const float*)d_in[9];
  const float* wdst = (const float*)d_in[10];
  const float* attsrc = (const float*)d_in[11];
  const float* attdst = (const float*)d_in[12];
  const float* cbias = (const float*)d_in[13];
  const float* wc = (const float*)d_in[14];
  const float* bc = (const float*)d_in[15];
  float* out = (float*)d_out;

  char* ws = (char*)d_ws;
  size_t off = 0;
  auto alloc = [&](size_t bytes) { size_t o = off; off += (bytes + 255) & ~(size_t)255; return o; };
  size_t o_rowptr = alloc((size_t)4 * (NN + 1) * 4);
  size_t o_next   = alloc((size_t)4 * NN * 4);
  size_t o_col    = alloc((size_t)4 * EE * 4);
  size_t o_deg    = alloc((size_t)4 * NN * 4);
  size_t o_v      = alloc((size_t)8 * 128 * 4);
  size_t o_hA     = alloc((size_t)NN * 128 * 4);
  size_t o_hB     = alloc((size_t)NN * 128 * 4);
  size_t o_sA     = alloc((size_t)NN * 4);
  size_t o_sB     = alloc((size_t)NN * 4);
  size_t o_Xa1    = alloc((size_t)NN * 128 * 4);
  size_t o_Xb1    = alloc((size_t)NN * 128 * 4);
  size_t o_Xa2    = alloc((size_t)NN * 128 * 4);
  size_t o_Xb2    = alloc((size_t)NN * 128 * 4);
  size_t o_pooled = alloc((size_t)GG * 256 * 4);
  size_t o_gcnt   = alloc((size_t)2 * GG * 4);

  int* rowptr = (int*)(ws + o_rowptr);
  int* nxt = (int*)(ws + o_next);
  int* col = (int*)(ws + o_col);
  int* deg = (int*)(ws + o_deg);
  float* vv = (float*)(ws + o_v);
  float* hA = (float*)(ws + o_hA);
  float* hB = (float*)(ws + o_hB);
  float* sA = (float*)(ws + o_sA);
  float* sB = (float*)(ws + o_sB);
  float* Xa1 = (float*)(ws + o_Xa1);
  float* Xb1 = (float*)(ws + o_Xb1);
  float* Xa2 = (float*)(ws + o_Xa2);
  float* Xb2 = (float*)(ws + o_Xb2);
  float* pooled = (float*)(ws + o_pooled);
  int* gcnt = (int*)(ws + o_gcnt);

  hipMemsetAsync(deg, 0, (size_t)4 * NN * 4, stream);
  hipMemsetAsync(pooled, 0, (size_t)GG * 256 * 4, stream);
  hipMemsetAsync(gcnt, 0, (size_t)2 * GG * 4, stream);

  v_kernel<<<8, 128, 0, stream>>>(wdst, attdst, vv);
  hist_kernel<<<dim3(1024, 4), 256, 0, stream>>>(ei0, ei1, ei2, ei3, deg);
  scan_kernel<<<4, 1024, 0, stream>>>(deg, rowptr, nxt);
  scatter_kernel<<<dim3(1024, 4), 256, 0, stream>>>(ei0, ei1, ei2, ei3, nxt, col);

  int gemm_gx = (NN + GBM - 1) / GBM;
  int agg_gx = (NN + 3) / 4;

  for (int L = 0; L < 2; L++) {
    const float* X0 = (L == 0) ? xA : Xa1;
    const float* X1 = (L == 0) ? xB : Xb1;
    float* Y0 = (L == 0) ? Xa1 : Xa2;
    float* Y1 = (L == 0) ? Xb1 : Xb2;

    // dst type 0: edge types 0 (src=A) and 2 (src=B)
    gemm_hs_kernel<<<dim3(gemm_gx, 1, 2), 256, 0, stream>>>(
        X0, wsrc + (size_t)(L * 4 + 0) * 16384, attsrc + (L * 4 + 0) * 128, hA, sA,
        X1, wsrc + (size_t)(L * 4 + 2) * 16384, attsrc + (L * 4 + 2) * 128, hB, sB);
    agg_kernel<<<agg_gx, 256, 0, stream>>>(
        X0,
        rowptr + (size_t)0 * (NN + 1), col + (size_t)0 * EE, hA, sA, vv + (L * 4 + 0) * 128, cbias + (L * 4 + 0) * 128,
        rowptr + (size_t)2 * (NN + 1), col + (size_t)2 * EE, hB, sB, vv + (L * 4 + 2) * 128, cbias + (L * 4 + 2) * 128,
        Y0);

    // dst type 1: edge types 1 (src=A) and 3 (src=B)
    gemm_hs_kernel<<<dim3(gemm_gx, 1, 2), 256, 0, stream>>>(
        X0, wsrc + (size_t)(L * 4 + 1) * 16384, attsrc + (L * 4 + 1) * 128, hA, sA,
        X1, wsrc + (size_t)(L * 4 + 3) * 16384, attsrc + (L * 4 + 3) * 128, hB, sB);
    agg_kernel<<<agg_gx, 256, 0, stream>>>(
        X1,
        rowptr + (size_t)1 * (NN + 1), col + (size_t)1 * EE, hA, sA, vv + (L * 4 + 1) * 128, cbias + (L * 4 + 1) * 128,
        rowptr + (size_t)3 * (NN + 1), col + (size_t)3 * EE, hB, sB, vv + (L * 4 + 3) * 128, cbias + (L * 4 + 3) * 128,
        Y1);
  }

  pool_kernel<<<agg_gx, 256, 0, stream>>>(Xa2, batchA, pooled, gcnt, 0);
  pool_kernel<<<agg_gx, 256, 0, stream>>>(Xb2, batchB, pooled, gcnt + GG, 128);
  final_kernel<<<3, 256, 0, stream>>>(pooled, gcnt, gcnt + GG, wc, bc, out);
}

// Round 2
// 1024.500 us; speedup vs baseline: 1.6815x; 1.6815x over previous
//
#include <hip/hip_runtime.h>
#include <hip/hip_bf16.h>

#define NN 50000
#define EE 500000
#define GG 64

__device__ __forceinline__ float wred_sum(float v) {
#pragma unroll
  for (int s = 32; s; s >>= 1) v += __shfl_xor(v, s, 64);
  return v;
}
__device__ __forceinline__ float wred_max(float v) {
#pragma unroll
  for (int s = 32; s; s >>= 1) v = fmaxf(v, __shfl_xor(v, s, 64));
  return v;
}

// ---- v = w_dst @ att_dst  (8 vectors of 128) ----
__global__ void v_kernel(const float* wdst, const float* adst, float* v) {
  int le = blockIdx.x;  // 0..7 = L*4+e
  int wid = threadIdx.x >> 6, lane = threadIdx.x & 63;  // 128 threads, 2 waves
  const float* W = wdst + (size_t)le * 128 * 128;
  const float* a = adst + le * 128;
  float a0 = a[lane], a1 = a[64 + lane];
  for (int k = wid; k < 128; k += 2) {
    float p = W[k * 128 + lane] * a0 + W[k * 128 + 64 + lane] * a1;
    p = wred_sum(p);
    if (lane == 0) v[le * 128 + k] = p;
  }
}

// ---- CSR build ----
__global__ void hist_kernel(const int* e0, const int* e1, const int* e2, const int* e3, int* deg) {
  int t = blockIdx.y;
  const int* dst = (t == 0 ? e0 : t == 1 ? e1 : t == 2 ? e2 : e3) + EE;
  for (int i = blockIdx.x * blockDim.x + threadIdx.x; i < EE; i += gridDim.x * blockDim.x)
    atomicAdd(&deg[t * NN + dst[i]], 1);
}

__global__ void scan_kernel(const int* deg, int* row_ptr, int* next) {
  int t = blockIdx.x;
  const int* d = deg + t * NN;
  int* rp = row_ptr + (size_t)t * (NN + 1);
  int* nx = next + t * NN;
  __shared__ int wsums[16];
  __shared__ int woff[16];
  __shared__ int carry;
  int tid = threadIdx.x, lane = tid & 63, wid = tid >> 6;
  if (tid == 0) { carry = 0; rp[0] = 0; }
  __syncthreads();
  for (int base = 0; base < NN; base += 1024) {
    int i = base + tid;
    int v = (i < NN) ? d[i] : 0;
    int orig = v;
#pragma unroll
    for (int s = 1; s < 64; s <<= 1) { int u = __shfl_up(v, s, 64); if (lane >= s) v += u; }
    if (lane == 63) wsums[wid] = v;
    __syncthreads();
    if (tid == 0) {
      int run = 0;
      for (int w = 0; w < 16; w++) { woff[w] = run; run += wsums[w]; }
      wsums[0] = run;
    }
    __syncthreads();
    int incl = carry + woff[wid] + v;
    if (i < NN) { rp[i + 1] = incl; nx[i] = incl - orig; }
    int ctot = wsums[0];
    __syncthreads();
    if (tid == 0) carry += ctot;
    __syncthreads();
  }
}

__global__ void scatter_kernel(const int* e0, const int* e1, const int* e2, const int* e3,
                               int* next, int* col) {
  int t = blockIdx.y;
  const int* ei = (t == 0 ? e0 : t == 1 ? e1 : t == 2 ? e2 : e3);
  const int* srcr = ei;
  const int* dstr = ei + EE;
  for (int i = blockIdx.x * blockDim.x + threadIdx.x; i < EE; i += gridDim.x * blockDim.x) {
    int dst = dstr[i];
    int pos = atomicAdd(&next[t * NN + dst], 1);
    col[(size_t)t * EE + pos] = srcr[i];
  }
}

// ---- graph boundaries via binary search on sorted batch vectors ----
__global__ void gbound_kernel(const int* batchA, const int* batchB, int* gbA, int* gbB) {
  int t = threadIdx.x;
  if (t >= 130) return;
  int which = t / 65, g = t % 65;
  const int* b = which ? batchB : batchA;
  int* gb = which ? gbB : gbA;
  int lo = 0, hi = NN;
  while (lo < hi) { int mid = (lo + hi) >> 1; if (b[mid] < g) lo = mid + 1; else hi = mid; }
  gb[g] = lo;
}

// ---- GEMM h = X @ W (M=50000,K=128,N=128) + fused s = h @ att ----
#define GBM 128
#define GBK 16
__global__ __launch_bounds__(256) void gemm_hs_kernel(
    const float* XA, const float* WA, const float* attA, float* hA_, float* sA_,
    const float* XB, const float* WB, const float* attB, float* hB_, float* sB_) {
  const float *X, *W, *att;
  float *h, *s_;
  if (blockIdx.z == 0) { X = XA; W = WA; att = attA; h = hA_; s_ = sA_; }
  else                 { X = XB; W = WB; att = attB; h = hB_; s_ = sB_; }
  __shared__ float Xs[GBM][GBK + 1];
  __shared__ float Ws[GBK][128];
  __shared__ float s_lds[GBM];
  int tid = threadIdx.x;
  int tx = tid & 15, ty = tid >> 4;
  int row0 = blockIdx.x * GBM;
  float acc[8][8] = {};
  float attr[8];
#pragma unroll
  for (int j = 0; j < 8; j++) attr[j] = att[tx * 8 + j];
  for (int kt = 0; kt < 128; kt += GBK) {
#pragma unroll
    for (int u = 0; u < 2; u++) {
      int f4 = tid + u * 256;
      int r = f4 >> 2, kg = f4 & 3;
      int row = row0 + r; row = row < NN ? row : NN - 1;
      float4 xv = *(const float4*)(X + (size_t)row * 128 + kt + kg * 4);
      Xs[r][kg * 4 + 0] = xv.x; Xs[r][kg * 4 + 1] = xv.y;
      Xs[r][kg * 4 + 2] = xv.z; Xs[r][kg * 4 + 3] = xv.w;
    }
#pragma unroll
    for (int u = 0; u < 2; u++) {
      int f4 = tid + u * 256;
      int r = f4 >> 5, cg = f4 & 31;
      float4 wv = *(const float4*)(W + (size_t)(kt + r) * 128 + cg * 4);
      *(float4*)(&Ws[r][cg * 4]) = wv;
    }
    __syncthreads();
#pragma unroll
    for (int k = 0; k < GBK; k++) {
      float a[8], b[8];
#pragma unroll
      for (int i = 0; i < 8; i++) a[i] = Xs[ty * 8 + i][k];
      float4 b0 = *(float4*)(&Ws[k][tx * 8]);
      float4 b1 = *(float4*)(&Ws[k][tx * 8 + 4]);
      b[0] = b0.x; b[1] = b0.y; b[2] = b0.z; b[3] = b0.w;
      b[4] = b1.x; b[5] = b1.y; b[6] = b1.z; b[7] = b1.w;
#pragma unroll
      for (int i = 0; i < 8; i++)
#pragma unroll
        for (int j = 0; j < 8; j++) acc[i][j] += a[i] * b[j];
    }
    __syncthreads();
  }
  if (tid < GBM) s_lds[tid] = 0.f;
  __syncthreads();
#pragma unroll
  for (int i = 0; i < 8; i++) {
    int row = row0 + ty * 8 + i;
    float sp = 0.f;
#pragma unroll
    for (int j = 0; j < 8; j++) sp += acc[i][j] * attr[j];
    if (row < NN) {
      float4 o0 = make_float4(acc[i][0], acc[i][1], acc[i][2], acc[i][3]);
      float4 o1 = make_float4(acc[i][4], acc[i][5], acc[i][6], acc[i][7]);
      *(float4*)(h + (size_t)row * 128 + tx * 8) = o0;
      *(float4*)(h + (size_t)row * 128 + tx * 8 + 4) = o1;
    }
    atomicAdd(&s_lds[ty * 8 + i], sp);
  }
  __syncthreads();
  if (tid < GBM) {
    int row = row0 + tid;
    if (row < NN) s_[row] = s_lds[tid];
  }
}

// ---- per-dst-node GAT aggregation, two edge types fused, + inter-type mean + relu ----
__global__ __launch_bounds__(256) void agg_kernel(
    const float* xdst,
    const int* rpA, const int* colA, const float* hA_, const float* sA_, const float* vA, const float* bA,
    const int* rpB, const int* colB, const float* hB_, const float* sB_, const float* vB, const float* bB,
    float* Y) {
  int wid = threadIdx.x >> 6, lane = threadIdx.x & 63;
  int node = blockIdx.x * 4 + wid;
  if (node >= NN) return;
  float x0 = xdst[(size_t)node * 128 + lane];
  float x1 = xdst[(size_t)node * 128 + 64 + lane];
  float out0 = 0.f, out1 = 0.f;
  for (int t = 0; t < 2; t++) {
    const int* rp = t ? rpB : rpA;
    const int* col = t ? colB : colA;
    const float* h = t ? hB_ : hA_;
    const float* ss = t ? sB_ : sA_;
    const float* v = t ? vB : vA;
    const float* b = t ? bB : bA;
    float sd = wred_sum(x0 * v[lane] + x1 * v[64 + lane]);
    int start = rp[node], end = rp[node + 1];
    int deg = end - start;
    float m = -3.4e38f;
    for (int i = start + lane; i < end; i += 64) {
      float s = ss[col[i]] + sd;
      s = (s >= 0.f) ? s : 0.2f * s;
      m = fmaxf(m, s);
    }
    m = wred_max(m);
    float dsum = 0.f, a0 = 0.f, a1 = 0.f;
    for (int base = start; base < end; base += 64) {
      int i = base + lane;
      float ex = 0.f;
      int src = 0;
      if (i < end) {
        src = col[i];
        float s = ss[src] + sd;
        s = (s >= 0.f) ? s : 0.2f * s;
        ex = expf(s - m);
      }
      dsum += ex;
      int cc = min(64, end - base);
      for (int j = 0; j < cc; j++) {
        int sj = __shfl(src, j, 64);
        float exj = __shfl(ex, j, 64);
        const float* hr = h + (size_t)sj * 128;
        a0 += exj * hr[lane];
        a1 += exj * hr[64 + lane];
      }
    }
    float denom = wred_sum(dsum);
    float inv = (deg > 0) ? 1.0f / (denom * (float)deg) : 0.f;
    out0 += 0.5f * (a0 * inv + b[lane]);
    out1 += 0.5f * (a1 * inv + b[64 + lane]);
  }
  Y[(size_t)node * 128 + lane] = fmaxf(out0, 0.f);
  Y[(size_t)node * 128 + 64 + lane] = fmaxf(out1, 0.f);
}

// ---- mean pooling over contiguous graph ranges (batch is sorted) ----
__global__ __launch_bounds__(256) void pool2_kernel(const float* XA_, const float* XB_,
                                                    const int* gbA, const int* gbB, float* pooled) {
  int t = blockIdx.y;
  const float* X = t ? XB_ : XA_;
  const int* gb = t ? gbB : gbA;
  int g = blockIdx.x;
  int n0 = gb[g], n1 = gb[g + 1];
  int wid = threadIdx.x >> 6, lane = threadIdx.x & 63;
  float s0 = 0.f, s1 = 0.f;
  for (int node = n0 + wid; node < n1; node += 4) {
    s0 += X[(size_t)node * 128 + lane];
    s1 += X[(size_t)node * 128 + 64 + lane];
  }
  __shared__ float red[4][128];
  red[wid][lane] = s0;
  red[wid][64 + lane] = s1;
  __syncthreads();
  if (wid == 0) {
    float a = red[0][lane] + red[1][lane] + red[2][lane] + red[3][lane];
    float b2 = red[0][64 + lane] + red[1][64 + lane] + red[2][64 + lane] + red[3][64 + lane];
    float inv = 1.f / fmaxf((float)(n1 - n0), 1.f);
    pooled[g * 256 + t * 128 + lane] = a * inv;
    pooled[g * 256 + t * 128 + 64 + lane] = b2 * inv;
  }
}

// ---- final linear ----
__global__ void final_kernel(const float* pooled, const float* wc, const float* bc, float* out) {
  int tid = blockIdx.x * blockDim.x + threadIdx.x;
  if (tid >= GG * 10) return;
  int g = tid / 10, o = tid % 10;
  float acc = bc[o];
  for (int k = 0; k < 256; k++) acc += pooled[g * 256 + k] * wc[k * 10 + o];
  out[g * 10 + o] = acc;
}

extern "C" void kernel_launch(void* const* d_in, const int* in_sizes, int n_in,
                              void* d_out, int out_size, void* d_ws, size_t ws_size,
                              hipStream_t stream) {
  const float* xA = (const float*)d_in[0];
  const float* xB = (const float*)d_in[1];
  const int* ei0 = (const int*)d_in[2];
  const int* ei1 = (const int*)d_in[3];
  const int* ei2 = (const int*)d_in[4];
  const int* ei3 = (const int*)d_in[5];
  const int* batchA = (const int*)d_in[6];
  const int* batchB = (const int*)d_in[7];
  const float* wsrc = (const float*)d_in[9];
  const float* wdst = (const float*)d_in[10];
  const float* attsrc = (const float*)d_in[11];
  const float* attdst = (const float*)d_in[12];
  const float* cbias = (const float*)d_in[13];
  const float* wc = (const float*)d_in[14];
  const float* bc = (const float*)d_in[15];
  float* out = (float*)d_out;

  char* ws = (char*)d_ws;
  size_t off = 0;
  auto alloc = [&](size_t bytes) { size_t o = off; off += (bytes + 255) & ~(size_t)255; return o; };
  size_t o_rowptr = alloc((size_t)4 * (NN + 1) * 4);
  size_t o_next   = alloc((size_t)4 * NN * 4);
  size_t o_col    = alloc((size_t)4 * EE * 4);
  size_t o_deg    = alloc((size_t)4 * NN * 4);
  size_t o_v      = alloc((size_t)8 * 128 * 4);
  size_t o_hA     = alloc((size_t)NN * 128 * 4);
  size_t o_hB     = alloc((size_t)NN * 128 * 4);
  size_t o_sA     = alloc((size_t)NN * 4);
  size_t o_sB     = alloc((size_t)NN * 4);
  size_t o_Xa1    = alloc((size_t)NN * 128 * 4);
  size_t o_Xb1    = alloc((size_t)NN * 128 * 4);
  size_t o_Xa2    = alloc((size_t)NN * 128 * 4);
  size_t o_Xb2    = alloc((size_t)NN * 128 * 4);
  size_t o_pooled = alloc((size_t)GG * 256 * 4);
  size_t o_gb     = alloc((size_t)2 * (GG + 1) * 4);

  int* rowptr = (int*)(ws + o_rowptr);
  int* nxt = (int*)(ws + o_next);
  int* col = (int*)(ws + o_col);
  int* deg = (int*)(ws + o_deg);
  float* vv = (float*)(ws + o_v);
  float* hA = (float*)(ws + o_hA);
  float* hB = (float*)(ws + o_hB);
  float* sA = (float*)(ws + o_sA);
  float* sB = (float*)(ws + o_sB);
  float* Xa1 = (float*)(ws + o_Xa1);
  float* Xb1 = (float*)(ws + o_Xb1);
  float* Xa2 = (float*)(ws + o_Xa2);
  float* Xb2 = (float*)(ws + o_Xb2);
  float* pooled = (float*)(ws + o_pooled);
  int* gbA = (int*)(ws + o_gb);
  int* gbB = gbA + (GG + 1);

  hipMemsetAsync(deg, 0, (size_t)4 * NN * 4, stream);

  v_kernel<<<8, 128, 0, stream>>>(wdst, attdst, vv);
  gbound_kernel<<<1, 192, 0, stream>>>(batchA, batchB, gbA, gbB);
  hist_kernel<<<dim3(1024, 4), 256, 0, stream>>>(ei0, ei1, ei2, ei3, deg);
  scan_kernel<<<4, 1024, 0, stream>>>(deg, rowptr, nxt);
  scatter_kernel<<<dim3(1024, 4), 256, 0, stream>>>(ei0, ei1, ei2, ei3, nxt, col);

  int gemm_gx = (NN + GBM - 1) / GBM;
  int agg_gx = (NN + 3) / 4;

  for (int L = 0; L < 2; L++) {
    const float* X0 = (L == 0) ? xA : Xa1;
    const float* X1 = (L == 0) ? xB : Xb1;
    float* Y0 = (L == 0) ? Xa1 : Xa2;
    float* Y1 = (L == 0) ? Xb1 : Xb2;

    // dst type 0: edge types 0 (src=A) and 2 (src=B)
    gemm_hs_kernel<<<dim3(gemm_gx, 1, 2), 256, 0, stream>>>(
        X0, wsrc + (size_t)(L * 4 + 0) * 16384, attsrc + (L * 4 + 0) * 128, hA, sA,
        X1, wsrc + (size_t)(L * 4 + 2) * 16384, attsrc + (L * 4 + 2) * 128, hB, sB);
    agg_kernel<<<agg_gx, 256, 0, stream>>>(
        X0,
        rowptr + (size_t)0 * (NN + 1), col + (size_t)0 * EE, hA, sA, vv + (L * 4 + 0) * 128, cbias + (L * 4 + 0) * 128,
        rowptr + (size_t)2 * (NN + 1), col + (size_t)2 * EE, hB, sB, vv + (L * 4 + 2) * 128, cbias + (L * 4 + 2) * 128,
        Y0);

    // dst type 1: edge types 1 (src=A) and 3 (src=B)
    gemm_hs_kernel<<<dim3(gemm_gx, 1, 2), 256, 0, stream>>>(
        X0, wsrc + (size_t)(L * 4 + 1) * 16384, attsrc + (L * 4 + 1) * 128, hA, sA,
        X1, wsrc + (size_t)(L * 4 + 3) * 16384, attsrc + (L * 4 + 3) * 128, hB, sB);
    agg_kernel<<<agg_gx, 256, 0, stream>>>(
        X1,
        rowptr + (size_t)1 * (NN + 1), col + (size_t)1 * EE, hA, sA, vv + (L * 4 + 1) * 128, cbias + (L * 4 + 1) * 128,
        rowptr + (size_t)3 * (NN + 1), col + (size_t)3 * EE, hB, sB, vv + (L * 4 + 3) * 128, cbias + (L * 4 + 3) * 128,
        Y1);
  }

  pool2_kernel<<<dim3(GG, 2), 256, 0, stream>>>(Xa2, Xb2, gbA, gbB, pooled);
  final_kernel<<<3, 256, 0, stream>>>(pooled, wc, bc, out);
}

// Round 3
// 922.649 us; speedup vs baseline: 1.8672x; 1.1104x over previous
//
#include <hip/hip_runtime.h>
#include <hip/hip_bf16.h>

#define NN 50000
#define EE 500000
#define GG 64
#define NSL 8      // dst slices
#define NGR 8      // edge groups
#define SLICE_N (NN / NSL)   // 6250
#define EPG (EE / NGR)       // 62500

typedef __attribute__((ext_vector_type(8))) short bf16x8;
typedef __attribute__((ext_vector_type(4))) float f32x4;

__device__ __forceinline__ float wred_sum(float v) {
#pragma unroll
  for (int s = 32; s; s >>= 1) v += __shfl_xor(v, s, 64);
  return v;
}
__device__ __forceinline__ float wred_max(float v) {
#pragma unroll
  for (int s = 32; s; s >>= 1) v = fmaxf(v, __shfl_xor(v, s, 64));
  return v;
}

__device__ __forceinline__ short f2bf(float x) {
  __hip_bfloat16 b = __float2bfloat16(x);
  return *reinterpret_cast<short*>(&b);
}
__device__ __forceinline__ float bf2f(short s) {
  __hip_bfloat16 b = *reinterpret_cast<__hip_bfloat16*>(&s);
  return __bfloat162float(b);
}

// ---- v = w_dst @ att_dst  (8 vectors of 128) ----
__global__ void v_kernel(const float* wdst, const float* adst, float* v) {
  int le = blockIdx.x;
  int wid = threadIdx.x >> 6, lane = threadIdx.x & 63;
  const float* W = wdst + (size_t)le * 128 * 128;
  const float* a = adst + le * 128;
  float a0 = a[lane], a1 = a[64 + lane];
  for (int k = wid; k < 128; k += 2) {
    float p = W[k * 128 + lane] * a0 + W[k * 128 + 64 + lane] * a1;
    p = wred_sum(p);
    if (lane == 0) v[le * 128 + k] = p;
  }
}

// ---- W convert: f32 [k][c] -> bf16 hi/lo transposed [c][k] ----
__global__ void wcvt_kernel(const float* wsrc, short* whiT, short* wloT) {
  int le = blockIdx.x;  // 0..7
  const float* W = wsrc + (size_t)le * 16384;
  for (int idx = threadIdx.x; idx < 16384; idx += blockDim.x) {
    int k = idx >> 7, c = idx & 127;
    float v = W[idx];
    short hi = f2bf(v);
    short lo = f2bf(v - bf2f(hi));
    whiT[(size_t)le * 16384 + c * 128 + k] = hi;
    wloT[(size_t)le * 16384 + c * 128 + k] = lo;
  }
}

// ---- CSR build: LDS histogram per (type, group, slice) — no global atomics ----
__global__ __launch_bounds__(256) void hist_kernel(const int* e0, const int* e1, const int* e2,
                                                   const int* e3, int* degc) {
  int t = blockIdx.y;
  int slice = blockIdx.x & (NSL - 1), g = blockIdx.x / NSL;
  const int* ei = (t == 0 ? e0 : t == 1 ? e1 : t == 2 ? e2 : e3);
  const int* dst = ei + EE;
  __shared__ int cnt[SLICE_N];
  for (int i = threadIdx.x; i < SLICE_N; i += 256) cnt[i] = 0;
  __syncthreads();
  int lo = slice * SLICE_N;
  int i0 = g * EPG, i1 = i0 + EPG;
  for (int i = i0 + threadIdx.x; i < i1; i += 256) {
    int d = dst[i] - lo;
    if ((unsigned)d < (unsigned)SLICE_N) atomicAdd(&cnt[d], 1);
  }
  __syncthreads();
  int* out = degc + ((size_t)(t * NGR + g)) * NN + lo;
  for (int i = threadIdx.x; i < SLICE_N; i += 256) out[i] = cnt[i];
}

// ---- scan: rowptr + in-place per-group bases ----
__global__ void scan_kernel(int* degc, int* row_ptr) {
  int t = blockIdx.x;
  int* rp = row_ptr + (size_t)t * (NN + 1);
  __shared__ int wsums[16];
  __shared__ int woff[16];
  __shared__ int carry;
  int tid = threadIdx.x, lane = tid & 63, wid = tid >> 6;
  if (tid == 0) { carry = 0; rp[0] = 0; }
  __syncthreads();
  for (int base = 0; base < NN; base += 1024) {
    int i = base + tid;
    int c[NGR];
    int v = 0;
    if (i < NN) {
#pragma unroll
      for (int g = 0; g < NGR; g++) {
        c[g] = degc[((size_t)(t * NGR + g)) * NN + i];
        v += c[g];
      }
    }
    int tot = v;
#pragma unroll
    for (int s = 1; s < 64; s <<= 1) { int u = __shfl_up(v, s, 64); if (lane >= s) v += u; }
    if (lane == 63) wsums[wid] = v;
    __syncthreads();
    if (tid == 0) {
      int run = 0;
      for (int w = 0; w < 16; w++) { woff[w] = run; run += wsums[w]; }
      wsums[0] = run;
    }
    __syncthreads();
    int incl = carry + woff[wid] + v;
    if (i < NN) {
      rp[i + 1] = incl;
      int run = incl - tot;
#pragma unroll
      for (int g = 0; g < NGR; g++) {
        degc[((size_t)(t * NGR + g)) * NN + i] = run;
        run += c[g];
      }
    }
    int ctot = wsums[0];
    __syncthreads();
    if (tid == 0) carry += ctot;
    __syncthreads();
  }
}

// ---- scatter: LDS cursors seeded from per-group bases — no global atomics ----
__global__ __launch_bounds__(256) void scatter_kernel(const int* e0, const int* e1, const int* e2,
                                                      const int* e3, const int* gbase, int* col) {
  int t = blockIdx.y;
  int slice = blockIdx.x & (NSL - 1), g = blockIdx.x / NSL;
  const int* ei = (t == 0 ? e0 : t == 1 ? e1 : t == 2 ? e2 : e3);
  const int* srcr = ei;
  const int* dstr = ei + EE;
  __shared__ int cur[SLICE_N];
  int lo = slice * SLICE_N;
  const int* gb = gbase + ((size_t)(t * NGR + g)) * NN + lo;
  for (int i = threadIdx.x; i < SLICE_N; i += 256) cur[i] = gb[i];
  __syncthreads();
  int* ct = col + (size_t)t * EE;
  int i0 = g * EPG, i1 = i0 + EPG;
  for (int i = i0 + threadIdx.x; i < i1; i += 256) {
    int d = dstr[i] - lo;
    if ((unsigned)d < (unsigned)SLICE_N) {
      int s = srcr[i];
      int pos = atomicAdd(&cur[d], 1);
      ct[pos] = s;
    }
  }
}

// ---- graph boundaries via binary search on sorted batch vectors ----
__global__ void gbound_kernel(const int* batchA, const int* batchB, int* gbA, int* gbB) {
  int t = threadIdx.x;
  if (t >= 130) return;
  int which = t / 65, g = t % 65;
  const int* b = which ? batchB : batchA;
  int* gb = which ? gbB : gbA;
  int lo = 0, hi = NN;
  while (lo < hi) { int mid = (lo + hi) >> 1; if (b[mid] < g) lo = mid + 1; else hi = mid; }
  gb[g] = lo;
}

// ---- MFMA GEMM h = X @ W (split-bf16, 3 terms) + fused s = h @ att ----
#define SWZ(row, kb) ((((row) << 6) + (kb)) ^ (((row) & 7) << 4))

__device__ __forceinline__ void cvt8(const float4 a, const float4 b, bf16x8& hv, bf16x8& lv) {
  short h;
  h = f2bf(a.x); hv[0] = h; lv[0] = f2bf(a.x - bf2f(h));
  h = f2bf(a.y); hv[1] = h; lv[1] = f2bf(a.y - bf2f(h));
  h = f2bf(a.z); hv[2] = h; lv[2] = f2bf(a.z - bf2f(h));
  h = f2bf(a.w); hv[3] = h; lv[3] = f2bf(a.w - bf2f(h));
  h = f2bf(b.x); hv[4] = h; lv[4] = f2bf(b.x - bf2f(h));
  h = f2bf(b.y); hv[5] = h; lv[5] = f2bf(b.y - bf2f(h));
  h = f2bf(b.z); hv[6] = h; lv[6] = f2bf(b.z - bf2f(h));
  h = f2bf(b.w); hv[7] = h; lv[7] = f2bf(b.w - bf2f(h));
}

__global__ __launch_bounds__(256) void gemm_hs_kernel(
    const float* XA, const short* WhA, const short* WlA, const float* attA, float* hAo, float* sAo,
    const float* XB, const short* WhB, const short* WlB, const float* attB, float* hBo, float* sBo) {
  const float *X, *att;
  const short *Wh, *Wl;
  float *h, *s_;
  if (blockIdx.z == 0) { X = XA; Wh = WhA; Wl = WlA; att = attA; h = hAo; s_ = sAo; }
  else                 { X = XB; Wh = WhB; Wl = WlB; att = attB; h = hBo; s_ = sBo; }

  __shared__ short Ah[128 * 32], Al[128 * 32], Bh[128 * 32], Bl[128 * 32];
  int tid = threadIdx.x;
  int l = tid & 63, w = tid >> 6;
  int arow = l & 15;
  int kb = (l >> 4) << 4;  // byte offset of k-frag
  int row0 = blockIdx.x * 128;

  f32x4 acc[2][8];
#pragma unroll
  for (int i = 0; i < 2; i++)
#pragma unroll
    for (int j = 0; j < 8; j++) acc[i][j] = (f32x4){0.f, 0.f, 0.f, 0.f};

  float attr[8];
#pragma unroll
  for (int j = 0; j < 8; j++) attr[j] = att[j * 16 + arow];

  int sr = tid >> 1, half = tid & 1;  // staging: row/col sr, k-half
  int xrow = row0 + sr; xrow = xrow < NN ? xrow : NN - 1;
  const float* xbase = X + (size_t)xrow * 128 + half * 16;
  const short* whbase = Wh + sr * 128 + half * 16;
  const short* wlbase = Wl + sr * 128 + half * 16;
  int soff0 = SWZ(sr, half * 32);
  int soff1 = SWZ(sr, half * 32 + 16);

  for (int kt = 0; kt < 128; kt += 32) {
    __syncthreads();
    // stage X -> hi/lo (convert in-kernel)
    float4 f0 = *(const float4*)(xbase + kt);
    float4 f1 = *(const float4*)(xbase + kt + 4);
    float4 f2 = *(const float4*)(xbase + kt + 8);
    float4 f3 = *(const float4*)(xbase + kt + 12);
    bf16x8 hv0, lv0, hv1, lv1;
    cvt8(f0, f1, hv0, lv0);
    cvt8(f2, f3, hv1, lv1);
    *(bf16x8*)((char*)Ah + soff0) = hv0;
    *(bf16x8*)((char*)Ah + soff1) = hv1;
    *(bf16x8*)((char*)Al + soff0) = lv0;
    *(bf16x8*)((char*)Al + soff1) = lv1;
    // stage W^T (already bf16 hi/lo in global)
    *(bf16x8*)((char*)Bh + soff0) = *(const bf16x8*)(whbase + kt);
    *(bf16x8*)((char*)Bh + soff1) = *(const bf16x8*)(whbase + kt + 8);
    *(bf16x8*)((char*)Bl + soff0) = *(const bf16x8*)(wlbase + kt);
    *(bf16x8*)((char*)Bl + soff1) = *(const bf16x8*)(wlbase + kt + 8);
    __syncthreads();

    bf16x8 ah[2], al[2];
#pragma unroll
    for (int i = 0; i < 2; i++) {
      int row = w * 32 + i * 16 + arow;
      ah[i] = *(bf16x8*)((char*)Ah + SWZ(row, kb));
      al[i] = *(bf16x8*)((char*)Al + SWZ(row, kb));
    }
#pragma unroll
    for (int j = 0; j < 8; j++) {
      int colr = j * 16 + arow;
      bf16x8 bh = *(bf16x8*)((char*)Bh + SWZ(colr, kb));
      bf16x8 bl = *(bf16x8*)((char*)Bl + SWZ(colr, kb));
#pragma unroll
      for (int i = 0; i < 2; i++) {
        acc[i][j] = __builtin_amdgcn_mfma_f32_16x16x32_bf16(ah[i], bh, acc[i][j], 0, 0, 0);
        acc[i][j] = __builtin_amdgcn_mfma_f32_16x16x32_bf16(ah[i], bl, acc[i][j], 0, 0, 0);
        acc[i][j] = __builtin_amdgcn_mfma_f32_16x16x32_bf16(al[i], bh, acc[i][j], 0, 0, 0);
      }
    }
  }

  // epilogue: h store + s = h @ att (reduce across 16-lane groups)
#pragma unroll
  for (int i = 0; i < 2; i++) {
#pragma unroll
    for (int r = 0; r < 4; r++) {
      int row = row0 + w * 32 + i * 16 + ((l >> 4) << 2) + r;
      float p = 0.f;
#pragma unroll
      for (int j = 0; j < 8; j++) p += acc[i][j][r] * attr[j];
      p += __shfl_xor(p, 1, 64);
      p += __shfl_xor(p, 2, 64);
      p += __shfl_xor(p, 4, 64);
      p += __shfl_xor(p, 8, 64);
      if (row < NN) {
        if (arow == 0) s_[row] = p;
        float* hp = h + (size_t)row * 128 + arow;
#pragma unroll
        for (int j = 0; j < 8; j++) hp[j * 16] = acc[i][j][r];
      }
    }
  }
}

// ---- per-dst-node GAT aggregation, two edge types fused, + inter-type mean + relu ----
__global__ __launch_bounds__(256) void agg_kernel(
    const float* xdst,
    const int* rpA, const int* colA, const float* hA_, const float* sA_, const float* vA, const float* bA,
    const int* rpB, const int* colB, const float* hB_, const float* sB_, const float* vB, const float* bB,
    float* Y) {
  int wid = threadIdx.x >> 6, lane = threadIdx.x & 63;
  int node = blockIdx.x * 4 + wid;
  if (node >= NN) return;
  float x0 = xdst[(size_t)node * 128 + lane];
  float x1 = xdst[(size_t)node * 128 + 64 + lane];
  float out0 = 0.f, out1 = 0.f;
  for (int t = 0; t < 2; t++) {
    const int* rp = t ? rpB : rpA;
    const int* col = t ? colB : colA;
    const float* h = t ? hB_ : hA_;
    const float* ss = t ? sB_ : sA_;
    const float* v = t ? vB : vA;
    const float* b = t ? bB : bA;
    float sd = wred_sum(x0 * v[lane] + x1 * v[64 + lane]);
    int start = rp[node], end = rp[node + 1];
    int deg = end - start;
    float m = -3.4e38f;
    for (int i = start + lane; i < end; i += 64) {
      float s = ss[col[i]] + sd;
      s = (s >= 0.f) ? s : 0.2f * s;
      m = fmaxf(m, s);
    }
    m = wred_max(m);
    float dsum = 0.f, a0 = 0.f, a1 = 0.f;
    for (int base = start; base < end; base += 64) {
      int i = base + lane;
      float ex = 0.f;
      int src = 0;
      if (i < end) {
        src = col[i];
        float s = ss[src] + sd;
        s = (s >= 0.f) ? s : 0.2f * s;
        ex = expf(s - m);
      }
      dsum += ex;
      int cc = min(64, end - base);
      for (int j = 0; j < cc; j++) {
        int sj = __shfl(src, j, 64);
        float exj = __shfl(ex, j, 64);
        const float* hr = h + (size_t)sj * 128;
        a0 += exj * hr[lane];
        a1 += exj * hr[64 + lane];
      }
    }
    float denom = wred_sum(dsum);
    float inv = (deg > 0) ? 1.0f / (denom * (float)deg) : 0.f;
    out0 += 0.5f * (a0 * inv + b[lane]);
    out1 += 0.5f * (a1 * inv + b[64 + lane]);
  }
  Y[(size_t)node * 128 + lane] = fmaxf(out0, 0.f);
  Y[(size_t)node * 128 + 64 + lane] = fmaxf(out1, 0.f);
}

// ---- mean pooling over contiguous graph ranges (batch is sorted) ----
__global__ __launch_bounds__(256) void pool2_kernel(const float* XA_, const float* XB_,
                                                    const int* gbA, const int* gbB, float* pooled) {
  int t = blockIdx.y;
  const float* X = t ? XB_ : XA_;
  const int* gb = t ? gbB : gbA;
  int g = blockIdx.x;
  int n0 = gb[g], n1 = gb[g + 1];
  int wid = threadIdx.x >> 6, lane = threadIdx.x & 63;
  float s0 = 0.f, s1 = 0.f;
  for (int node = n0 + wid; node < n1; node += 4) {
    s0 += X[(size_t)node * 128 + lane];
    s1 += X[(size_t)node * 128 + 64 + lane];
  }
  __shared__ float red[4][128];
  red[wid][lane] = s0;
  red[wid][64 + lane] = s1;
  __syncthreads();
  if (wid == 0) {
    float a = red[0][lane] + red[1][lane] + red[2][lane] + red[3][lane];
    float b2 = red[0][64 + lane] + red[1][64 + lane] + red[2][64 + lane] + red[3][64 + lane];
    float inv = 1.f / fmaxf((float)(n1 - n0), 1.f);
    pooled[g * 256 + t * 128 + lane] = a * inv;
    pooled[g * 256 + t * 128 + 64 + lane] = b2 * inv;
  }
}

// ---- final linear ----
__global__ void final_kernel(const float* pooled, const float* wc, const float* bc, float* out) {
  int tid = blockIdx.x * blockDim.x + threadIdx.x;
  if (tid >= GG * 10) return;
  int g = tid / 10, o = tid % 10;
  float acc = bc[o];
  for (int k = 0; k < 256; k++) acc += pooled[g * 256 + k] * wc[k * 10 + o];
  out[g * 10 + o] = acc;
}

extern "C" void kernel_launch(void* const* d_in, const int* in_sizes, int n_in,
                              void* d_out, int out_size, void* d_ws, size_t ws_size,
                              hipStream_t stream) {
  const float* xA = (const float*)d_in[0];
  const float* xB = (const float*)d_in[1];
  const int* ei0 = (const int*)d_in[2];
  const int* ei1 = (const int*)d_in[3];
  const int* ei2 = (const int*)d_in[4];
  const int* ei3 = (const int*)d_in[5];
  const int* batchA = (const int*)d_in[6];
  const int* batchB = (const int*)d_in[7];
  const float* wsrc = (const float*)d_in[9];
  const float* wdst = (const float*)d_in[10];
  const float* attsrc = (const float*)d_in[11];
  const float* attdst = (const float*)d_in[12];
  const float* cbias = (const float*)d_in[13];
  const float* wc = (const float*)d_in[14];
  const float* bc = (const float*)d_in[15];
  float* out = (float*)d_out;

  char* ws = (char*)d_ws;
  size_t off = 0;
  auto alloc = [&](size_t bytes) { size_t o = off; off += (bytes + 255) & ~(size_t)255; return o; };
  size_t o_rowptr = alloc((size_t)4 * (NN + 1) * 4);
  size_t o_col    = alloc((size_t)4 * EE * 4);
  size_t o_v      = alloc((size_t)8 * 128 * 4);
  size_t o_whiT   = alloc((size_t)8 * 16384 * 2);
  size_t o_wloT   = alloc((size_t)8 * 16384 * 2);
  size_t o_hA     = alloc((size_t)NN * 128 * 4);   // also aliased as degc before GEMMs
  size_t o_hB     = alloc((size_t)NN * 128 * 4);
  size_t o_sA     = alloc((size_t)NN * 4);
  size_t o_sB     = alloc((size_t)NN * 4);
  size_t o_Xa1    = alloc((size_t)NN * 128 * 4);
  size_t o_Xb1    = alloc((size_t)NN * 128 * 4);
  size_t o_Xa2    = alloc((size_t)NN * 128 * 4);
  size_t o_Xb2    = alloc((size_t)NN * 128 * 4);
  size_t o_pooled = alloc((size_t)GG * 256 * 4);
  size_t o_gb     = alloc((size_t)2 * (GG + 1) * 4);

  int* rowptr = (int*)(ws + o_rowptr);
  int* col = (int*)(ws + o_col);
  float* vv = (float*)(ws + o_v);
  short* whiT = (short*)(ws + o_whiT);
  short* wloT = (short*)(ws + o_wloT);
  float* hA = (float*)(ws + o_hA);
  float* hB = (float*)(ws + o_hB);
  int* degc = (int*)(ws + o_hA);  // alias: dead once GEMMs start (stream-ordered)
  float* sA = (float*)(ws + o_sA);
  float* sB = (float*)(ws + o_sB);
  float* Xa1 = (float*)(ws + o_Xa1);
  float* Xb1 = (float*)(ws + o_Xb1);
  float* Xa2 = (float*)(ws + o_Xa2);
  float* Xb2 = (float*)(ws + o_Xb2);
  float* pooled = (float*)(ws + o_pooled);
  int* gbA = (int*)(ws + o_gb);
  int* gbB = gbA + (GG + 1);

  v_kernel<<<8, 128, 0, stream>>>(wdst, attdst, vv);
  wcvt_kernel<<<8, 256, 0, stream>>>(wsrc, whiT, wloT);
  gbound_kernel<<<1, 192, 0, stream>>>(batchA, batchB, gbA, gbB);
  hist_kernel<<<dim3(NSL * NGR, 4), 256, 0, stream>>>(ei0, ei1, ei2, ei3, degc);
  scan_kernel<<<4, 1024, 0, stream>>>(degc, rowptr);
  scatter_kernel<<<dim3(NSL * NGR, 4), 256, 0, stream>>>(ei0, ei1, ei2, ei3, degc, col);

  int gemm_gx = (NN + 127) / 128;
  int agg_gx = (NN + 3) / 4;

  for (int L = 0; L < 2; L++) {
    const float* X0 = (L == 0) ? xA : Xa1;
    const float* X1 = (L == 0) ? xB : Xb1;
    float* Y0 = (L == 0) ? Xa1 : Xa2;
    float* Y1 = (L == 0) ? Xb1 : Xb2;

    // dst type 0: edge types 0 (src=A) and 2 (src=B)
    gemm_hs_kernel<<<dim3(gemm_gx, 1, 2), 256, 0, stream>>>(
        X0, whiT + (size_t)(L * 4 + 0) * 16384, wloT + (size_t)(L * 4 + 0) * 16384,
        attsrc + (L * 4 + 0) * 128, hA, sA,
        X1, whiT + (size_t)(L * 4 + 2) * 16384, wloT + (size_t)(L * 4 + 2) * 16384,
        attsrc + (L * 4 + 2) * 128, hB, sB);
    agg_kernel<<<agg_gx, 256, 0, stream>>>(
        X0,
        rowptr + (size_t)0 * (NN + 1), col + (size_t)0 * EE, hA, sA, vv + (L * 4 + 0) * 128, cbias + (L * 4 + 0) * 128,
        rowptr + (size_t)2 * (NN + 1), col + (size_t)2 * EE, hB, sB, vv + (L * 4 + 2) * 128, cbias + (L * 4 + 2) * 128,
        Y0);

    // dst type 1: edge types 1 (src=A) and 3 (src=B)
    gemm_hs_kernel<<<dim3(gemm_gx, 1, 2), 256, 0, stream>>>(
        X0, whiT + (size_t)(L * 4 + 1) * 16384, wloT + (size_t)(L * 4 + 1) * 16384,
        attsrc + (L * 4 + 1) * 128, hA, sA,
        X1, whiT + (size_t)(L * 4 + 3) * 16384, wloT + (size_t)(L * 4 + 3) * 16384,
        attsrc + (L * 4 + 3) * 128, hB, sB);
    agg_kernel<<<agg_gx, 256, 0, stream>>>(
        X1,
        rowptr + (size_t)1 * (NN + 1), col + (size_t)1 * EE, hA, sA, vv + (L * 4 + 1) * 128, cbias + (L * 4 + 1) * 128,
        rowptr + (size_t)3 * (NN + 1), col + (size_t)3 * EE, hB, sB, vv + (L * 4 + 3) * 128, cbias + (L * 4 + 3) * 128,
        Y1);
  }

  pool2_kernel<<<dim3(GG, 2), 256, 0, stream>>>(Xa2, Xb2, gbA, gbB, pooled);
  final_kernel<<<3, 256, 0, stream>>>(pooled, wc, bc, out);
}

// Round 4
// 677.755 us; speedup vs baseline: 2.5418x; 1.3613x over previous
//
#include <hip/hip_runtime.h>
#include <hip/hip_bf16.h>

#define NN 50000
#define EE 500000
#define GG 64
#define NSL 50        // dst slices (SPAN nodes each)
#define SPAN 1000
#define NCH 125       // edge chunks
#define EPG (EE / NCH)  // 4000
#define NCNT (4 * NSL * NCH)  // 25000

typedef __attribute__((ext_vector_type(8))) short bf16x8;
typedef __attribute__((ext_vector_type(4))) float f32x4;

__device__ __forceinline__ float wred_sum(float v) {
#pragma unroll
  for (int s = 32; s; s >>= 1) v += __shfl_xor(v, s, 64);
  return v;
}
__device__ __forceinline__ float wred_max(float v) {
#pragma unroll
  for (int s = 32; s; s >>= 1) v = fmaxf(v, __shfl_xor(v, s, 64));
  return v;
}

__device__ __forceinline__ short f2bf(float x) {
  __hip_bfloat16 b = __float2bfloat16(x);
  return *reinterpret_cast<short*>(&b);
}
__device__ __forceinline__ float bf2f(unsigned short s) {
  __hip_bfloat16 b = *reinterpret_cast<__hip_bfloat16*>(&s);
  return __bfloat162float(b);
}

// ---- v = w_dst @ att_dst  (8 vectors of 128) ----
__global__ void v_kernel(const float* wdst, const float* adst, float* v) {
  int le = blockIdx.x;
  int wid = threadIdx.x >> 6, lane = threadIdx.x & 63;
  const float* W = wdst + (size_t)le * 128 * 128;
  const float* a = adst + le * 128;
  float a0 = a[lane], a1 = a[64 + lane];
  for (int k = wid; k < 128; k += 2) {
    float p = W[k * 128 + lane] * a0 + W[k * 128 + 64 + lane] * a1;
    p = wred_sum(p);
    if (lane == 0) v[le * 128 + k] = p;
  }
}

// ---- W convert: f32 [k][c] -> bf16 hi/lo transposed [c][k] ----
__global__ void wcvt_kernel(const float* wsrc, short* whiT, short* wloT) {
  int le = blockIdx.x;
  const float* W = wsrc + (size_t)le * 16384;
  for (int idx = threadIdx.x; idx < 16384; idx += blockDim.x) {
    int k = idx >> 7, c = idx & 127;
    float v = W[idx];
    short hi = f2bf(v);
    short lo = f2bf(v - bf2f((unsigned short)hi));
    whiT[(size_t)le * 16384 + c * 128 + k] = hi;
    wloT[(size_t)le * 16384 + c * 128 + k] = lo;
  }
}

// ======== CSR build: radix partition by dst slice, then per-slice build ========

// phase 0: per (type, chunk) count edges per slice
__global__ __launch_bounds__(256) void pcount_kernel(const int* e0, const int* e1, const int* e2,
                                                     const int* e3, int* counts) {
  int t = blockIdx.y, ch = blockIdx.x;
  const int* ei = (t == 0 ? e0 : t == 1 ? e1 : t == 2 ? e2 : e3);
  const int* dst = ei + EE;
  __shared__ int cnt[NSL];
  for (int i = threadIdx.x; i < NSL; i += 256) cnt[i] = 0;
  __syncthreads();
  int i0 = ch * EPG;
  for (int i = i0 + threadIdx.x; i < i0 + EPG; i += 256) atomicAdd(&cnt[dst[i] / SPAN], 1);
  __syncthreads();
  for (int sl = threadIdx.x; sl < NSL; sl += 256) counts[(t * NSL + sl) * NCH + ch] = cnt[sl];
}

// phase 0.5: one-block exclusive scan over counts (order t,slice,chunk); emit sliceptr
__global__ void pscan_kernel(int* counts, int* sliceptr) {
  __shared__ int psum[256];
  int tid = threadIdx.x;
  const int PER = (NCNT + 255) / 256;  // 98
  int base = tid * PER;
  int s = 0;
  for (int k = 0; k < PER; k++) {
    int idx = base + k;
    if (idx < NCNT) s += counts[idx];
  }
  psum[tid] = s;
  __syncthreads();
  if (tid == 0) {
    int run = 0;
    for (int i = 0; i < 256; i++) { int v = psum[i]; psum[i] = run; run += v; }
  }
  __syncthreads();
  int run = psum[tid];
  for (int k = 0; k < PER; k++) {
    int idx = base + k;
    if (idx < NCNT) { int v = counts[idx]; counts[idx] = run; run += v; }
  }
  __syncthreads();
  for (int g = tid; g < 4 * NSL; g += 256)
    sliceptr[(g / NSL) * (NSL + 1) + (g % NSL)] = counts[g * NCH];
  if (tid < 4) sliceptr[tid * (NSL + 1) + NSL] = (tid + 1) * EE;
}

// phase 1: partition edges into slice-clustered (src,dst) pairs
__global__ __launch_bounds__(256) void ppart_kernel(const int* e0, const int* e1, const int* e2,
                                                    const int* e3, const int* counts, int2* pairs) {
  int t = blockIdx.y, ch = blockIdx.x;
  const int* ei = (t == 0 ? e0 : t == 1 ? e1 : t == 2 ? e2 : e3);
  const int* srcr = ei;
  const int* dstr = ei + EE;
  __shared__ int cur[NSL];
  for (int i = threadIdx.x; i < NSL; i += 256) cur[i] = counts[(t * NSL + i) * NCH + ch];
  __syncthreads();
  int i0 = ch * EPG;
  for (int i = i0 + threadIdx.x; i < i0 + EPG; i += 256) {
    int d = dstr[i], s = srcr[i];
    int pos = atomicAdd(&cur[d / SPAN], 1);
    pairs[pos] = make_int2(s, d);
  }
}

// phase 2: per (type, slice) build rowptr + col
__global__ __launch_bounds__(256) void pbuild_kernel(const int2* pairs, const int* sliceptr,
                                                     int* rowptr, int* col) {
  int t = blockIdx.y, sl = blockIdx.x;
  int n0 = sl * SPAN;
  int e0 = sliceptr[t * (NSL + 1) + sl], e1 = sliceptr[t * (NSL + 1) + sl + 1];
  int tid = threadIdx.x, lane = tid & 63, wid = tid >> 6;
  __shared__ int cnt[SPAN];
  __shared__ int wsum[4];
  for (int i = tid; i < SPAN; i += 256) cnt[i] = 0;
  __syncthreads();
  for (int e = e0 + tid; e < e1; e += 256) atomicAdd(&cnt[pairs[e].y - n0], 1);
  __syncthreads();
  // exclusive scan of cnt[SPAN]: threads 0..249 own 4 entries each
  int s0 = 0, s1 = 0, s2 = 0, s3 = 0, tot = 0;
  if (tid < SPAN / 4) {
    s0 = cnt[tid * 4]; s1 = cnt[tid * 4 + 1]; s2 = cnt[tid * 4 + 2]; s3 = cnt[tid * 4 + 3];
    tot = s0 + s1 + s2 + s3;
  }
  int v = tot;
#pragma unroll
  for (int sft = 1; sft < 64; sft <<= 1) { int u = __shfl_up(v, sft, 64); if (lane >= sft) v += u; }
  if (lane == 63) wsum[wid] = v;
  __syncthreads();
  int woffv = (wid > 0 ? wsum[0] : 0) + (wid > 1 ? wsum[1] : 0) + (wid > 2 ? wsum[2] : 0);
  int excl = v + woffv - tot;
  __syncthreads();
  if (tid < SPAN / 4) {
    cnt[tid * 4] = excl;
    cnt[tid * 4 + 1] = excl + s0;
    cnt[tid * 4 + 2] = excl + s0 + s1;
    cnt[tid * 4 + 3] = excl + s0 + s1 + s2;
  }
  __syncthreads();
  int base = e0 - t * EE;
  for (int n = tid; n < SPAN; n += 256) rowptr[(size_t)t * (NN + 1) + n0 + n] = base + cnt[n];
  if (sl == NSL - 1 && tid == 0) rowptr[(size_t)t * (NN + 1) + NN] = EE;
  __syncthreads();
  int* ct = col + (size_t)t * EE;
  for (int e = e0 + tid; e < e1; e += 256) {
    int2 p = pairs[e];
    int pos = base + atomicAdd(&cnt[p.y - n0], 1);
    ct[pos] = p.x;
  }
}

// ---- graph boundaries via binary search on sorted batch vectors ----
__global__ void gbound_kernel(const int* batchA, const int* batchB, int* gbA, int* gbB) {
  int t = threadIdx.x;
  if (t >= 130) return;
  int which = t / 65, g = t % 65;
  const int* b = which ? batchB : batchA;
  int* gb = which ? gbB : gbA;
  int lo = 0, hi = NN;
  while (lo < hi) { int mid = (lo + hi) >> 1; if (b[mid] < g) lo = mid + 1; else hi = mid; }
  gb[g] = lo;
}

// ---- MFMA GEMM h = X @ W (split-bf16, 3 terms) + fused s = h @ att; h stored bf16 ----
#define SWZ(row, kb) ((((row) << 6) + (kb)) ^ (((row) & 7) << 4))

__device__ __forceinline__ void cvt8(const float4 a, const float4 b, bf16x8& hv, bf16x8& lv) {
  short h;
  h = f2bf(a.x); hv[0] = h; lv[0] = f2bf(a.x - bf2f((unsigned short)h));
  h = f2bf(a.y); hv[1] = h; lv[1] = f2bf(a.y - bf2f((unsigned short)h));
  h = f2bf(a.z); hv[2] = h; lv[2] = f2bf(a.z - bf2f((unsigned short)h));
  h = f2bf(a.w); hv[3] = h; lv[3] = f2bf(a.w - bf2f((unsigned short)h));
  h = f2bf(b.x); hv[4] = h; lv[4] = f2bf(b.x - bf2f((unsigned short)h));
  h = f2bf(b.y); hv[5] = h; lv[5] = f2bf(b.y - bf2f((unsigned short)h));
  h = f2bf(b.z); hv[6] = h; lv[6] = f2bf(b.z - bf2f((unsigned short)h));
  h = f2bf(b.w); hv[7] = h; lv[7] = f2bf(b.w - bf2f((unsigned short)h));
}

__global__ __launch_bounds__(256) void gemm_hs_kernel(
    const float* XA, const short* WhA, const short* WlA, const float* attA, unsigned short* hAo, float* sAo,
    const float* XB, const short* WhB, const short* WlB, const float* attB, unsigned short* hBo, float* sBo) {
  const float *X, *att;
  const short *Wh, *Wl;
  unsigned short* h;
  float* s_;
  if (blockIdx.z == 0) { X = XA; Wh = WhA; Wl = WlA; att = attA; h = hAo; s_ = sAo; }
  else                 { X = XB; Wh = WhB; Wl = WlB; att = attB; h = hBo; s_ = sBo; }

  __shared__ short Ah[128 * 32], Al[128 * 32], Bh[128 * 32], Bl[128 * 32];
  int tid = threadIdx.x;
  int l = tid & 63, w = tid >> 6;
  int arow = l & 15;
  int kb = (l >> 4) << 4;
  int row0 = blockIdx.x * 128;

  f32x4 acc[2][8];
#pragma unroll
  for (int i = 0; i < 2; i++)
#pragma unroll
    for (int j = 0; j < 8; j++) acc[i][j] = (f32x4){0.f, 0.f, 0.f, 0.f};

  float attr[8];
#pragma unroll
  for (int j = 0; j < 8; j++) attr[j] = att[j * 16 + arow];

  int sr = tid >> 1, half = tid & 1;
  int xrow = row0 + sr; xrow = xrow < NN ? xrow : NN - 1;
  const float* xbase = X + (size_t)xrow * 128 + half * 16;
  const short* whbase = Wh + sr * 128 + half * 16;
  const short* wlbase = Wl + sr * 128 + half * 16;
  int soff0 = SWZ(sr, half * 32);
  int soff1 = SWZ(sr, half * 32 + 16);

  for (int kt = 0; kt < 128; kt += 32) {
    __syncthreads();
    float4 f0 = *(const float4*)(xbase + kt);
    float4 f1 = *(const float4*)(xbase + kt + 4);
    float4 f2 = *(const float4*)(xbase + kt + 8);
    float4 f3 = *(const float4*)(xbase + kt + 12);
    bf16x8 hv0, lv0, hv1, lv1;
    cvt8(f0, f1, hv0, lv0);
    cvt8(f2, f3, hv1, lv1);
    *(bf16x8*)((char*)Ah + soff0) = hv0;
    *(bf16x8*)((char*)Ah + soff1) = hv1;
    *(bf16x8*)((char*)Al + soff0) = lv0;
    *(bf16x8*)((char*)Al + soff1) = lv1;
    *(bf16x8*)((char*)Bh + soff0) = *(const bf16x8*)(whbase + kt);
    *(bf16x8*)((char*)Bh + soff1) = *(const bf16x8*)(whbase + kt + 8);
    *(bf16x8*)((char*)Bl + soff0) = *(const bf16x8*)(wlbase + kt);
    *(bf16x8*)((char*)Bl + soff1) = *(const bf16x8*)(wlbase + kt + 8);
    __syncthreads();

    bf16x8 ah[2], al[2];
#pragma unroll
    for (int i = 0; i < 2; i++) {
      int row = w * 32 + i * 16 + arow;
      ah[i] = *(bf16x8*)((char*)Ah + SWZ(row, kb));
      al[i] = *(bf16x8*)((char*)Al + SWZ(row, kb));
    }
#pragma unroll
    for (int j = 0; j < 8; j++) {
      int colr = j * 16 + arow;
      bf16x8 bh = *(bf16x8*)((char*)Bh + SWZ(colr, kb));
      bf16x8 bl = *(bf16x8*)((char*)Bl + SWZ(colr, kb));
#pragma unroll
      for (int i = 0; i < 2; i++) {
        acc[i][j] = __builtin_amdgcn_mfma_f32_16x16x32_bf16(ah[i], bh, acc[i][j], 0, 0, 0);
        acc[i][j] = __builtin_amdgcn_mfma_f32_16x16x32_bf16(ah[i], bl, acc[i][j], 0, 0, 0);
        acc[i][j] = __builtin_amdgcn_mfma_f32_16x16x32_bf16(al[i], bh, acc[i][j], 0, 0, 0);
      }
    }
  }

#pragma unroll
  for (int i = 0; i < 2; i++) {
#pragma unroll
    for (int r = 0; r < 4; r++) {
      int row = row0 + w * 32 + i * 16 + ((l >> 4) << 2) + r;
      float p = 0.f;
#pragma unroll
      for (int j = 0; j < 8; j++) p += acc[i][j][r] * attr[j];
      p += __shfl_xor(p, 1, 64);
      p += __shfl_xor(p, 2, 64);
      p += __shfl_xor(p, 4, 64);
      p += __shfl_xor(p, 8, 64);
      if (row < NN) {
        if (arow == 0) s_[row] = p;
        unsigned short* hp = h + (size_t)row * 128 + arow;
#pragma unroll
        for (int j = 0; j < 8; j++) hp[j * 16] = (unsigned short)f2bf(acc[i][j][r]);
      }
    }
  }
}

// ---- per-dst-node GAT aggregation (bf16 h gather), inter-type mean + relu ----
__global__ __launch_bounds__(256) void agg_kernel(
    const float* xdst,
    const int* rpA, const int* colA, const unsigned short* hA_, const float* sA_, const float* vA, const float* bA,
    const int* rpB, const int* colB, const unsigned short* hB_, const float* sB_, const float* vB, const float* bB,
    float* Y) {
  int wid = threadIdx.x >> 6, lane = threadIdx.x & 63;
  int node = blockIdx.x * 4 + wid;
  if (node >= NN) return;
  float2 xv = *(const float2*)(xdst + (size_t)node * 128 + 2 * lane);
  float out0 = 0.f, out1 = 0.f;
  for (int t = 0; t < 2; t++) {
    const int* rp = t ? rpB : rpA;
    const int* col = t ? colB : colA;
    const unsigned short* h = t ? hB_ : hA_;
    const float* ss = t ? sB_ : sA_;
    const float* v = t ? vB : vA;
    const float* b = t ? bB : bA;
    float2 v2 = *(const float2*)(v + 2 * lane);
    float sd = wred_sum(xv.x * v2.x + xv.y * v2.y);
    int start = rp[node], end = rp[node + 1];
    int deg = end - start;
    float m = -3.4e38f;
    for (int i = start + lane; i < end; i += 64) {
      float s = ss[col[i]] + sd;
      s = (s >= 0.f) ? s : 0.2f * s;
      m = fmaxf(m, s);
    }
    m = wred_max(m);
    float dsum = 0.f, a0 = 0.f, a1 = 0.f;
    for (int base = start; base < end; base += 64) {
      int i = base + lane;
      float ex = 0.f;
      int src = 0;
      if (i < end) {
        src = col[i];
        float s = ss[src] + sd;
        s = (s >= 0.f) ? s : 0.2f * s;
        ex = __expf(s - m);
      }
      dsum += ex;
      int cc = min(64, end - base);
      for (int j = 0; j < cc; j++) {
        int sj = __shfl(src, j, 64);
        float exj = __shfl(ex, j, 64);
        ushort2 u = *(const ushort2*)(h + (size_t)sj * 128 + 2 * lane);
        a0 += exj * bf2f(u.x);
        a1 += exj * bf2f(u.y);
      }
    }
    float denom = wred_sum(dsum);
    float inv = (deg > 0) ? 1.0f / (denom * (float)deg) : 0.f;
    float2 bv = *(const float2*)(b + 2 * lane);
    out0 += 0.5f * (a0 * inv + bv.x);
    out1 += 0.5f * (a1 * inv + bv.y);
  }
  float2 o = make_float2(fmaxf(out0, 0.f), fmaxf(out1, 0.f));
  *(float2*)(Y + (size_t)node * 128 + 2 * lane) = o;
}

// ---- mean pooling over contiguous graph ranges (batch is sorted) ----
__global__ __launch_bounds__(256) void pool2_kernel(const float* XA_, const float* XB_,
                                                    const int* gbA, const int* gbB, float* pooled) {
  int t = blockIdx.y;
  const float* X = t ? XB_ : XA_;
  const int* gb = t ? gbB : gbA;
  int g = blockIdx.x;
  int n0 = gb[g], n1 = gb[g + 1];
  int wid = threadIdx.x >> 6, lane = threadIdx.x & 63;
  float s0 = 0.f, s1 = 0.f;
  for (int node = n0 + wid; node < n1; node += 4) {
    s0 += X[(size_t)node * 128 + lane];
    s1 += X[(size_t)node * 128 + 64 + lane];
  }
  __shared__ float red[4][128];
  red[wid][lane] = s0;
  red[wid][64 + lane] = s1;
  __syncthreads();
  if (wid == 0) {
    float a = red[0][lane] + red[1][lane] + red[2][lane] + red[3][lane];
    float b2 = red[0][64 + lane] + red[1][64 + lane] + red[2][64 + lane] + red[3][64 + lane];
    float inv = 1.f / fmaxf((float)(n1 - n0), 1.f);
    pooled[g * 256 + t * 128 + lane] = a * inv;
    pooled[g * 256 + t * 128 + 64 + lane] = b2 * inv;
  }
}

// ---- final linear ----
__global__ void final_kernel(const float* pooled, const float* wc, const float* bc, float* out) {
  int tid = blockIdx.x * blockDim.x + threadIdx.x;
  if (tid >= GG * 10) return;
  int g = tid / 10, o = tid % 10;
  float acc = bc[o];
  for (int k = 0; k < 256; k++) acc += pooled[g * 256 + k] * wc[k * 10 + o];
  out[g * 10 + o] = acc;
}

extern "C" void kernel_launch(void* const* d_in, const int* in_sizes, int n_in,
                              void* d_out, int out_size, void* d_ws, size_t ws_size,
                              hipStream_t stream) {
  const float* xA = (const float*)d_in[0];
  const float* xB = (const float*)d_in[1];
  const int* ei0 = (const int*)d_in[2];
  const int* ei1 = (const int*)d_in[3];
  const int* ei2 = (const int*)d_in[4];
  const int* ei3 = (const int*)d_in[5];
  const int* batchA = (const int*)d_in[6];
  const int* batchB = (const int*)d_in[7];
  const float* wsrc = (const float*)d_in[9];
  const float* wdst = (const float*)d_in[10];
  const float* attsrc = (const float*)d_in[11];
  const float* attdst = (const float*)d_in[12];
  const float* cbias = (const float*)d_in[13];
  const float* wc = (const float*)d_in[14];
  const float* bc = (const float*)d_in[15];
  float* out = (float*)d_out;

  char* ws = (char*)d_ws;
  size_t off = 0;
  auto alloc = [&](size_t bytes) { size_t o = off; off += (bytes + 255) & ~(size_t)255; return o; };
  size_t o_rowptr = alloc((size_t)4 * (NN + 1) * 4);
  size_t o_col    = alloc((size_t)4 * EE * 4);
  size_t o_cnts   = alloc((size_t)NCNT * 4);
  size_t o_slptr  = alloc((size_t)4 * (NSL + 1) * 4);
  size_t o_v      = alloc((size_t)8 * 128 * 4);
  size_t o_whiT   = alloc((size_t)8 * 16384 * 2);
  size_t o_wloT   = alloc((size_t)8 * 16384 * 2);
  size_t o_hA     = alloc((size_t)NN * 128 * 2);   // bf16; pairs alias hA+hB pre-GEMM
  size_t o_hB     = alloc((size_t)NN * 128 * 2);
  size_t o_sA     = alloc((size_t)NN * 4);
  size_t o_sB     = alloc((size_t)NN * 4);
  size_t o_Xa1    = alloc((size_t)NN * 128 * 4);
  size_t o_Xb1    = alloc((size_t)NN * 128 * 4);
  size_t o_Xa2    = alloc((size_t)NN * 128 * 4);
  size_t o_Xb2    = alloc((size_t)NN * 128 * 4);
  size_t o_pooled = alloc((size_t)GG * 256 * 4);
  size_t o_gb     = alloc((size_t)2 * (GG + 1) * 4);

  int* rowptr = (int*)(ws + o_rowptr);
  int* col = (int*)(ws + o_col);
  int* counts = (int*)(ws + o_cnts);
  int* sliceptr = (int*)(ws + o_slptr);
  float* vv = (float*)(ws + o_v);
  short* whiT = (short*)(ws + o_whiT);
  short* wloT = (short*)(ws + o_wloT);
  unsigned short* hA = (unsigned short*)(ws + o_hA);
  unsigned short* hB = (unsigned short*)(ws + o_hB);
  int2* pairs = (int2*)(ws + o_hA);  // 16 MB alias over hA+hB (dead until GEMMs)
  float* sA = (float*)(ws + o_sA);
  float* sB = (float*)(ws + o_sB);
  float* Xa1 = (float*)(ws + o_Xa1);
  float* Xb1 = (float*)(ws + o_Xb1);
  float* Xa2 = (float*)(ws + o_Xa2);
  float* Xb2 = (float*)(ws + o_Xb2);
  float* pooled = (float*)(ws + o_pooled);
  int* gbA = (int*)(ws + o_gb);
  int* gbB = gbA + (GG + 1);

  v_kernel<<<8, 128, 0, stream>>>(wdst, attdst, vv);
  wcvt_kernel<<<8, 256, 0, stream>>>(wsrc, whiT, wloT);
  gbound_kernel<<<1, 192, 0, stream>>>(batchA, batchB, gbA, gbB);
  pcount_kernel<<<dim3(NCH, 4), 256, 0, stream>>>(ei0, ei1, ei2, ei3, counts);
  pscan_kernel<<<1, 256, 0, stream>>>(counts, sliceptr);
  ppart_kernel<<<dim3(NCH, 4), 256, 0, stream>>>(ei0, ei1, ei2, ei3, counts, pairs);
  pbuild_kernel<<<dim3(NSL, 4), 256, 0, stream>>>(pairs, sliceptr, rowptr, col);

  int gemm_gx = (NN + 127) / 128;
  int agg_gx = (NN + 3) / 4;

  for (int L = 0; L < 2; L++) {
    const float* X0 = (L == 0) ? xA : Xa1;
    const float* X1 = (L == 0) ? xB : Xb1;
    float* Y0 = (L == 0) ? Xa1 : Xa2;
    float* Y1 = (L == 0) ? Xb1 : Xb2;

    gemm_hs_kernel<<<dim3(gemm_gx, 1, 2), 256, 0, stream>>>(
        X0, whiT + (size_t)(L * 4 + 0) * 16384, wloT + (size_t)(L * 4 + 0) * 16384,
        attsrc + (L * 4 + 0) * 128, hA, sA,
        X1, whiT + (size_t)(L * 4 + 2) * 16384, wloT + (size_t)(L * 4 + 2) * 16384,
        attsrc + (L * 4 + 2) * 128, hB, sB);
    agg_kernel<<<agg_gx, 256, 0, stream>>>(
        X0,
        rowptr + (size_t)0 * (NN + 1), col + (size_t)0 * EE, hA, sA, vv + (L * 4 + 0) * 128, cbias + (L * 4 + 0) * 128,
        rowptr + (size_t)2 * (NN + 1), col + (size_t)2 * EE, hB, sB, vv + (L * 4 + 2) * 128, cbias + (L * 4 + 2) * 128,
        Y0);

    gemm_hs_kernel<<<dim3(gemm_gx, 1, 2), 256, 0, stream>>>(
        X0, whiT + (size_t)(L * 4 + 1) * 16384, wloT + (size_t)(L * 4 + 1) * 16384,
        attsrc + (L * 4 + 1) * 128, hA, sA,
        X1, whiT + (size_t)(L * 4 + 3) * 16384, wloT + (size_t)(L * 4 + 3) * 16384,
        attsrc + (L * 4 + 3) * 128, hB, sB);
    agg_kernel<<<agg_gx, 256, 0, stream>>>(
        X1,
        rowptr + (size_t)1 * (NN + 1), col + (size_t)1 * EE, hA, sA, vv + (L * 4 + 1) * 128, cbias + (L * 4 + 1) * 128,
        rowptr + (size_t)3 * (NN + 1), col + (size_t)3 * EE, hB, sB, vv + (L * 4 + 3) * 128, cbias + (L * 4 + 3) * 128,
        Y1);
  }

  pool2_kernel<<<dim3(GG, 2), 256, 0, stream>>>(Xa2, Xb2, gbA, gbB, pooled);
  final_kernel<<<3, 256, 0, stream>>>(pooled, wc, bc, out);
}

// Round 5
// 551.777 us; speedup vs baseline: 3.1222x; 1.2283x over previous
//
#include <hip/hip_runtime.h>
#include <hip/hip_bf16.h>

#define NN 50000
#define EE 500000
#define GG 64
#define NSL 50        // dst slices (SPAN nodes each)
#define SPAN 1000
#define NCH 125       // edge chunks
#define EPG (EE / NCH)  // 4000
#define NCNT (4 * NSL * NCH)  // 25000

typedef __attribute__((ext_vector_type(8))) short bf16x8;
typedef __attribute__((ext_vector_type(4))) float f32x4;

__device__ __forceinline__ float wred_sum(float v) {
#pragma unroll
  for (int s = 32; s; s >>= 1) v += __shfl_xor(v, s, 64);
  return v;
}
__device__ __forceinline__ float wred_max(float v) {
#pragma unroll
  for (int s = 32; s; s >>= 1) v = fmaxf(v, __shfl_xor(v, s, 64));
  return v;
}

__device__ __forceinline__ short f2bf(float x) {
  __hip_bfloat16 b = __float2bfloat16(x);
  return *reinterpret_cast<short*>(&b);
}
__device__ __forceinline__ float bf2f(unsigned short s) {
  __hip_bfloat16 b = *reinterpret_cast<__hip_bfloat16*>(&s);
  return __bfloat162float(b);
}

// ---- v = w_dst @ att_dst  (8 vectors of 128) ----
__global__ void v_kernel(const float* wdst, const float* adst, float* v) {
  int le = blockIdx.x;
  int wid = threadIdx.x >> 6, lane = threadIdx.x & 63;
  const float* W = wdst + (size_t)le * 128 * 128;
  const float* a = adst + le * 128;
  float a0 = a[lane], a1 = a[64 + lane];
  for (int k = wid; k < 128; k += 2) {
    float p = W[k * 128 + lane] * a0 + W[k * 128 + 64 + lane] * a1;
    p = wred_sum(p);
    if (lane == 0) v[le * 128 + k] = p;
  }
}

// ---- W convert: f32 [k][c] -> bf16 hi/lo transposed [c][k] ----
__global__ void wcvt_kernel(const float* wsrc, short* whiT, short* wloT) {
  int le = blockIdx.x;
  const float* W = wsrc + (size_t)le * 16384;
  for (int idx = threadIdx.x; idx < 16384; idx += blockDim.x) {
    int k = idx >> 7, c = idx & 127;
    float v = W[idx];
    short hi = f2bf(v);
    short lo = f2bf(v - bf2f((unsigned short)hi));
    whiT[(size_t)le * 16384 + c * 128 + k] = hi;
    wloT[(size_t)le * 16384 + c * 128 + k] = lo;
  }
}

// ======== CSR build: radix partition by dst slice, then per-slice build ========

__global__ __launch_bounds__(256) void pcount_kernel(const int* e0, const int* e1, const int* e2,
                                                     const int* e3, int* counts) {
  int t = blockIdx.y, ch = blockIdx.x;
  const int* ei = (t == 0 ? e0 : t == 1 ? e1 : t == 2 ? e2 : e3);
  const int* dst = ei + EE;
  __shared__ int cnt[NSL];
  for (int i = threadIdx.x; i < NSL; i += 256) cnt[i] = 0;
  __syncthreads();
  int i0 = ch * EPG;
  for (int i = i0 + threadIdx.x; i < i0 + EPG; i += 256) atomicAdd(&cnt[dst[i] / SPAN], 1);
  __syncthreads();
  for (int sl = threadIdx.x; sl < NSL; sl += 256) counts[(t * NSL + sl) * NCH + ch] = cnt[sl];
}

__global__ void pscan_kernel(int* counts, int* sliceptr) {
  __shared__ int psum[256];
  int tid = threadIdx.x;
  const int PER = (NCNT + 255) / 256;
  int base = tid * PER;
  int s = 0;
  for (int k = 0; k < PER; k++) {
    int idx = base + k;
    if (idx < NCNT) s += counts[idx];
  }
  psum[tid] = s;
  __syncthreads();
  if (tid == 0) {
    int run = 0;
    for (int i = 0; i < 256; i++) { int v = psum[i]; psum[i] = run; run += v; }
  }
  __syncthreads();
  int run = psum[tid];
  for (int k = 0; k < PER; k++) {
    int idx = base + k;
    if (idx < NCNT) { int v = counts[idx]; counts[idx] = run; run += v; }
  }
  __syncthreads();
  for (int g = tid; g < 4 * NSL; g += 256)
    sliceptr[(g / NSL) * (NSL + 1) + (g % NSL)] = counts[g * NCH];
  if (tid < 4) sliceptr[tid * (NSL + 1) + NSL] = (tid + 1) * EE;
}

__global__ __launch_bounds__(256) void ppart_kernel(const int* e0, const int* e1, const int* e2,
                                                    const int* e3, const int* counts, int2* pairs) {
  int t = blockIdx.y, ch = blockIdx.x;
  const int* ei = (t == 0 ? e0 : t == 1 ? e1 : t == 2 ? e2 : e3);
  const int* srcr = ei;
  const int* dstr = ei + EE;
  __shared__ int cur[NSL];
  for (int i = threadIdx.x; i < NSL; i += 256) cur[i] = counts[(t * NSL + i) * NCH + ch];
  __syncthreads();
  int i0 = ch * EPG;
  for (int i = i0 + threadIdx.x; i < i0 + EPG; i += 256) {
    int d = dstr[i], s = srcr[i];
    int pos = atomicAdd(&cur[d / SPAN], 1);
    pairs[pos] = make_int2(s, d);
  }
}

__global__ __launch_bounds__(256) void pbuild_kernel(const int2* pairs, const int* sliceptr,
                                                     int* rowptr, int* col) {
  int t = blockIdx.y, sl = blockIdx.x;
  int n0 = sl * SPAN;
  int e0 = sliceptr[t * (NSL + 1) + sl], e1 = sliceptr[t * (NSL + 1) + sl + 1];
  int tid = threadIdx.x, lane = tid & 63, wid = tid >> 6;
  __shared__ int cnt[SPAN];
  __shared__ int wsum[4];
  for (int i = tid; i < SPAN; i += 256) cnt[i] = 0;
  __syncthreads();
  for (int e = e0 + tid; e < e1; e += 256) atomicAdd(&cnt[pairs[e].y - n0], 1);
  __syncthreads();
  int s0 = 0, s1 = 0, s2 = 0, s3 = 0, tot = 0;
  if (tid < SPAN / 4) {
    s0 = cnt[tid * 4]; s1 = cnt[tid * 4 + 1]; s2 = cnt[tid * 4 + 2]; s3 = cnt[tid * 4 + 3];
    tot = s0 + s1 + s2 + s3;
  }
  int v = tot;
#pragma unroll
  for (int sft = 1; sft < 64; sft <<= 1) { int u = __shfl_up(v, sft, 64); if (lane >= sft) v += u; }
  if (lane == 63) wsum[wid] = v;
  __syncthreads();
  int woffv = (wid > 0 ? wsum[0] : 0) + (wid > 1 ? wsum[1] : 0) + (wid > 2 ? wsum[2] : 0);
  int excl = v + woffv - tot;
  __syncthreads();
  if (tid < SPAN / 4) {
    cnt[tid * 4] = excl;
    cnt[tid * 4 + 1] = excl + s0;
    cnt[tid * 4 + 2] = excl + s0 + s1;
    cnt[tid * 4 + 3] = excl + s0 + s1 + s2;
  }
  __syncthreads();
  int base = e0 - t * EE;
  for (int n = tid; n < SPAN; n += 256) rowptr[(size_t)t * (NN + 1) + n0 + n] = base + cnt[n];
  if (sl == NSL - 1 && tid == 0) rowptr[(size_t)t * (NN + 1) + NN] = EE;
  __syncthreads();
  int* ct = col + (size_t)t * EE;
  for (int e = e0 + tid; e < e1; e += 256) {
    int2 p = pairs[e];
    int pos = base + atomicAdd(&cnt[p.y - n0], 1);
    ct[pos] = p.x;
  }
}

// ---- graph boundaries via binary search on sorted batch vectors ----
__global__ void gbound_kernel(const int* batchA, const int* batchB, int* gbA, int* gbB) {
  int t = threadIdx.x;
  if (t >= 130) return;
  int which = t / 65, g = t % 65;
  const int* b = which ? batchB : batchA;
  int* gb = which ? gbB : gbA;
  int lo = 0, hi = NN;
  while (lo < hi) { int mid = (lo + hi) >> 1; if (b[mid] < g) lo = mid + 1; else hi = mid; }
  gb[g] = lo;
}

// ---- MFMA GEMM h = X @ W (split-bf16, 3 terms) + fused s = h @ att; h stored bf16 ----
#define SWZ(row, kb) ((((row) << 6) + (kb)) ^ (((row) & 7) << 4))

__device__ __forceinline__ void cvt8(const float4 a, const float4 b, bf16x8& hv, bf16x8& lv) {
  short h;
  h = f2bf(a.x); hv[0] = h; lv[0] = f2bf(a.x - bf2f((unsigned short)h));
  h = f2bf(a.y); hv[1] = h; lv[1] = f2bf(a.y - bf2f((unsigned short)h));
  h = f2bf(a.z); hv[2] = h; lv[2] = f2bf(a.z - bf2f((unsigned short)h));
  h = f2bf(a.w); hv[3] = h; lv[3] = f2bf(a.w - bf2f((unsigned short)h));
  h = f2bf(b.x); hv[4] = h; lv[4] = f2bf(b.x - bf2f((unsigned short)h));
  h = f2bf(b.y); hv[5] = h; lv[5] = f2bf(b.y - bf2f((unsigned short)h));
  h = f2bf(b.z); hv[6] = h; lv[6] = f2bf(b.z - bf2f((unsigned short)h));
  h = f2bf(b.w); hv[7] = h; lv[7] = f2bf(b.w - bf2f((unsigned short)h));
}

__global__ __launch_bounds__(256) void gemm_hs_kernel(
    const float* XA, const short* WhA, const short* WlA, const float* attA, unsigned short* hAo, float* sAo,
    const float* XB, const short* WhB, const short* WlB, const float* attB, unsigned short* hBo, float* sBo) {
  const float *X, *att;
  const short *Wh, *Wl;
  unsigned short* h;
  float* s_;
  if (blockIdx.z == 0) { X = XA; Wh = WhA; Wl = WlA; att = attA; h = hAo; s_ = sAo; }
  else                 { X = XB; Wh = WhB; Wl = WlB; att = attB; h = hBo; s_ = sBo; }

  __shared__ short Ah[128 * 32], Al[128 * 32], Bh[128 * 32], Bl[128 * 32];
  int tid = threadIdx.x;
  int l = tid & 63, w = tid >> 6;
  int arow = l & 15;
  int kb = (l >> 4) << 4;
  int row0 = blockIdx.x * 128;

  f32x4 acc[2][8];
#pragma unroll
  for (int i = 0; i < 2; i++)
#pragma unroll
    for (int j = 0; j < 8; j++) acc[i][j] = (f32x4){0.f, 0.f, 0.f, 0.f};

  float attr[8];
#pragma unroll
  for (int j = 0; j < 8; j++) attr[j] = att[j * 16 + arow];

  int sr = tid >> 1, half = tid & 1;
  int xrow = row0 + sr; xrow = xrow < NN ? xrow : NN - 1;
  const float* xbase = X + (size_t)xrow * 128 + half * 16;
  const short* whbase = Wh + sr * 128 + half * 16;
  const short* wlbase = Wl + sr * 128 + half * 16;
  int soff0 = SWZ(sr, half * 32);
  int soff1 = SWZ(sr, half * 32 + 16);

  for (int kt = 0; kt < 128; kt += 32) {
    __syncthreads();
    float4 f0 = *(const float4*)(xbase + kt);
    float4 f1 = *(const float4*)(xbase + kt + 4);
    float4 f2 = *(const float4*)(xbase + kt + 8);
    float4 f3 = *(const float4*)(xbase + kt + 12);
    bf16x8 hv0, lv0, hv1, lv1;
    cvt8(f0, f1, hv0, lv0);
    cvt8(f2, f3, hv1, lv1);
    *(bf16x8*)((char*)Ah + soff0) = hv0;
    *(bf16x8*)((char*)Ah + soff1) = hv1;
    *(bf16x8*)((char*)Al + soff0) = lv0;
    *(bf16x8*)((char*)Al + soff1) = lv1;
    *(bf16x8*)((char*)Bh + soff0) = *(const bf16x8*)(whbase + kt);
    *(bf16x8*)((char*)Bh + soff1) = *(const bf16x8*)(whbase + kt + 8);
    *(bf16x8*)((char*)Bl + soff0) = *(const bf16x8*)(wlbase + kt);
    *(bf16x8*)((char*)Bl + soff1) = *(const bf16x8*)(wlbase + kt + 8);
    __syncthreads();

    bf16x8 ah[2], al[2];
#pragma unroll
    for (int i = 0; i < 2; i++) {
      int row = w * 32 + i * 16 + arow;
      ah[i] = *(bf16x8*)((char*)Ah + SWZ(row, kb));
      al[i] = *(bf16x8*)((char*)Al + SWZ(row, kb));
    }
#pragma unroll
    for (int j = 0; j < 8; j++) {
      int colr = j * 16 + arow;
      bf16x8 bh = *(bf16x8*)((char*)Bh + SWZ(colr, kb));
      bf16x8 bl = *(bf16x8*)((char*)Bl + SWZ(colr, kb));
#pragma unroll
      for (int i = 0; i < 2; i++) {
        acc[i][j] = __builtin_amdgcn_mfma_f32_16x16x32_bf16(ah[i], bh, acc[i][j], 0, 0, 0);
        acc[i][j] = __builtin_amdgcn_mfma_f32_16x16x32_bf16(ah[i], bl, acc[i][j], 0, 0, 0);
        acc[i][j] = __builtin_amdgcn_mfma_f32_16x16x32_bf16(al[i], bh, acc[i][j], 0, 0, 0);
      }
    }
  }

#pragma unroll
  for (int i = 0; i < 2; i++) {
#pragma unroll
    for (int r = 0; r < 4; r++) {
      int row = row0 + w * 32 + i * 16 + ((l >> 4) << 2) + r;
      float p = 0.f;
#pragma unroll
      for (int j = 0; j < 8; j++) p += acc[i][j][r] * attr[j];
      p += __shfl_xor(p, 1, 64);
      p += __shfl_xor(p, 2, 64);
      p += __shfl_xor(p, 4, 64);
      p += __shfl_xor(p, 8, 64);
      if (row < NN) {
        if (arow == 0) s_[row] = p;
        unsigned short* hp = h + (size_t)row * 128 + arow;
#pragma unroll
        for (int j = 0; j < 8; j++) hp[j * 16] = (unsigned short)f2bf(acc[i][j][r]);
      }
    }
  }
}

// ---- per-dst-node GAT aggregation: 4 edges/iter (16-lane groups, uint4 row loads) ----
__global__ __launch_bounds__(256) void agg_kernel(
    const float* xdst,
    const int* rpA, const int* colA, const unsigned short* hA_, const float* sA_, const float* vA, const float* bA,
    const int* rpB, const int* colB, const unsigned short* hB_, const float* sB_, const float* vB, const float* bB,
    float* Y) {
  int wid = threadIdx.x >> 6, lane = threadIdx.x & 63;
  int node = blockIdx.x * 4 + wid;
  if (node >= NN) return;
  int grp = lane >> 4;        // 0..3: edge sub-group
  int d0 = (lane & 15) * 8;   // this lane's 8 dims
  const float* xr = xdst + (size_t)node * 128 + d0;
  float4 xv0 = *(const float4*)(xr);
  float4 xv1 = *(const float4*)(xr + 4);
  float outv[8] = {0.f, 0.f, 0.f, 0.f, 0.f, 0.f, 0.f, 0.f};

  for (int t = 0; t < 2; t++) {
    const int* rp = t ? rpB : rpA;
    const int* col = t ? colB : colA;
    const unsigned short* h = t ? hB_ : hA_;
    const float* ss = t ? sB_ : sA_;
    const float* v = t ? vB : vA;
    float4 v0 = *(const float4*)(v + d0);
    float4 v1 = *(const float4*)(v + d0 + 4);
    float part = xv0.x * v0.x + xv0.y * v0.y + xv0.z * v0.z + xv0.w * v0.w +
                 xv1.x * v1.x + xv1.y * v1.y + xv1.z * v1.z + xv1.w * v1.w;
    float sd = wred_sum(part) * 0.25f;  // each dim counted 4x across groups

    int start = rp[node], end = rp[node + 1];
    int deg = end - start;
    int nch = (deg + 63) >> 6;

    // pass 1: max, caching (src, score) of first 4 chunks in scalars
    int srcC0 = 0, srcC1 = 0, srcC2 = 0, srcC3 = 0;
    float sC0 = 0.f, sC1 = 0.f, sC2 = 0.f, sC3 = 0.f;
    float m = -3.4e38f;
    {
      int i = start + lane;
      if (i < end) { srcC0 = col[i]; float s = ss[srcC0] + sd; s = s >= 0.f ? s : 0.2f * s; sC0 = s; m = fmaxf(m, s); }
      i += 64;
      if (i < end) { srcC1 = col[i]; float s = ss[srcC1] + sd; s = s >= 0.f ? s : 0.2f * s; sC1 = s; m = fmaxf(m, s); }
      i += 64;
      if (i < end) { srcC2 = col[i]; float s = ss[srcC2] + sd; s = s >= 0.f ? s : 0.2f * s; sC2 = s; m = fmaxf(m, s); }
      i += 64;
      if (i < end) { srcC3 = col[i]; float s = ss[srcC3] + sd; s = s >= 0.f ? s : 0.2f * s; sC3 = s; m = fmaxf(m, s); }
      for (i = start + 256 + lane; i < end; i += 64) {
        float s = ss[col[i]] + sd; s = s >= 0.f ? s : 0.2f * s; m = fmaxf(m, s);
      }
    }
    m = wred_max(m);

    float dsum = 0.f;
    float a[8] = {0.f, 0.f, 0.f, 0.f, 0.f, 0.f, 0.f, 0.f};
    for (int k = 0; k < nch; k++) {
      int i = start + k * 64 + lane;
      int src = 0; float s = 0.f;
      if (k == 0)      { src = srcC0; s = sC0; }
      else if (k == 1) { src = srcC1; s = sC1; }
      else if (k == 2) { src = srcC2; s = sC2; }
      else if (k == 3) { src = srcC3; s = sC3; }
      else if (i < end) { src = col[i]; s = ss[src] + sd; s = s >= 0.f ? s : 0.2f * s; }
      float ex = (i < end) ? __expf(s - m) : 0.f;
      dsum += ex;
      int cc = min(64, end - (start + k * 64));
      for (int j = 0; j < cc; j += 4) {
        int jj = j + grp;
        int je = jj < cc ? jj : cc - 1;
        int sj = __shfl(src, je, 64);
        float exj = __shfl(ex, je, 64);
        if (jj >= cc) exj = 0.f;
        uint4 uv = *(const uint4*)(h + (size_t)sj * 128 + d0);
        float f;
        f = __uint_as_float(uv.x << 16);          a[0] += exj * f;
        f = __uint_as_float(uv.x & 0xffff0000u);  a[1] += exj * f;
        f = __uint_as_float(uv.y << 16);          a[2] += exj * f;
        f = __uint_as_float(uv.y & 0xffff0000u);  a[3] += exj * f;
        f = __uint_as_float(uv.z << 16);          a[4] += exj * f;
        f = __uint_as_float(uv.z & 0xffff0000u);  a[5] += exj * f;
        f = __uint_as_float(uv.w << 16);          a[6] += exj * f;
        f = __uint_as_float(uv.w & 0xffff0000u);  a[7] += exj * f;
      }
    }
    float denom = wred_sum(dsum);
    float inv = (deg > 0) ? 0.5f / (denom * (float)deg) : 0.f;
#pragma unroll
    for (int k2 = 0; k2 < 8; k2++) outv[k2] += a[k2] * inv;
  }

  // reduce the 4 edge-groups, add biases once, relu, store
#pragma unroll
  for (int k2 = 0; k2 < 8; k2++) {
    outv[k2] += __shfl_xor(outv[k2], 16, 64);
    outv[k2] += __shfl_xor(outv[k2], 32, 64);
  }
  const float* bA8 = bA + d0;
  const float* bB8 = bB + d0;
#pragma unroll
  for (int k2 = 0; k2 < 8; k2++)
    outv[k2] = fmaxf(outv[k2] + 0.5f * (bA8[k2] + bB8[k2]), 0.f);
  if (grp == 0) {
    float4 o0 = make_float4(outv[0], outv[1], outv[2], outv[3]);
    float4 o1 = make_float4(outv[4], outv[5], outv[6], outv[7]);
    *(float4*)(Y + (size_t)node * 128 + d0) = o0;
    *(float4*)(Y + (size_t)node * 128 + d0 + 4) = o1;
  }
}

// ---- mean pooling over contiguous graph ranges (batch is sorted) ----
__global__ __launch_bounds__(256) void pool2_kernel(const float* XA_, const float* XB_,
                                                    const int* gbA, const int* gbB, float* pooled) {
  int t = blockIdx.y;
  const float* X = t ? XB_ : XA_;
  const int* gb = t ? gbB : gbA;
  int g = blockIdx.x;
  int n0 = gb[g], n1 = gb[g + 1];
  int wid = threadIdx.x >> 6, lane = threadIdx.x & 63;
  float s0 = 0.f, s1 = 0.f;
  for (int node = n0 + wid; node < n1; node += 4) {
    s0 += X[(size_t)node * 128 + lane];
    s1 += X[(size_t)node * 128 + 64 + lane];
  }
  __shared__ float red[4][128];
  red[wid][lane] = s0;
  red[wid][64 + lane] = s1;
  __syncthreads();
  if (wid == 0) {
    float a = red[0][lane] + red[1][lane] + red[2][lane] + red[3][lane];
    float b2 = red[0][64 + lane] + red[1][64 + lane] + red[2][64 + lane] + red[3][64 + lane];
    float inv = 1.f / fmaxf((float)(n1 - n0), 1.f);
    pooled[g * 256 + t * 128 + lane] = a * inv;
    pooled[g * 256 + t * 128 + 64 + lane] = b2 * inv;
  }
}

// ---- final linear ----
__global__ void final_kernel(const float* pooled, const float* wc, const float* bc, float* out) {
  int tid = blockIdx.x * blockDim.x + threadIdx.x;
  if (tid >= GG * 10) return;
  int g = tid / 10, o = tid % 10;
  float acc = bc[o];
  for (int k = 0; k < 256; k++) acc += pooled[g * 256 + k] * wc[k * 10 + o];
  out[g * 10 + o] = acc;
}

extern "C" void kernel_launch(void* const* d_in, const int* in_sizes, int n_in,
                              void* d_out, int out_size, void* d_ws, size_t ws_size,
                              hipStream_t stream) {
  const float* xA = (const float*)d_in[0];
  const float* xB = (const float*)d_in[1];
  const int* ei0 = (const int*)d_in[2];
  const int* ei1 = (const int*)d_in[3];
  const int* ei2 = (const int*)d_in[4];
  const int* ei3 = (const int*)d_in[5];
  const int* batchA = (const int*)d_in[6];
  const int* batchB = (const int*)d_in[7];
  const float* wsrc = (const float*)d_in[9];
  const float* wdst = (const float*)d_in[10];
  const float* attsrc = (const float*)d_in[11];
  const float* attdst = (const float*)d_in[12];
  const float* cbias = (const float*)d_in[13];
  const float* wc = (const float*)d_in[14];
  const float* bc = (const float*)d_in[15];
  float* out = (float*)d_out;

  char* ws = (char*)d_ws;
  size_t off = 0;
  auto alloc = [&](size_t bytes) { size_t o = off; off += (bytes + 255) & ~(size_t)255; return o; };
  size_t o_rowptr = alloc((size_t)4 * (NN + 1) * 4);
  size_t o_col    = alloc((size_t)4 * EE * 4);
  size_t o_cnts   = alloc((size_t)NCNT * 4);
  size_t o_slptr  = alloc((size_t)4 * (NSL + 1) * 4);
  size_t o_v      = alloc((size_t)8 * 128 * 4);
  size_t o_whiT   = alloc((size_t)8 * 16384 * 2);
  size_t o_wloT   = alloc((size_t)8 * 16384 * 2);
  size_t o_hA     = alloc((size_t)NN * 128 * 2);   // bf16; pairs alias hA+hB pre-GEMM
  size_t o_hB     = alloc((size_t)NN * 128 * 2);
  size_t o_sA     = alloc((size_t)NN * 4);
  size_t o_sB     = alloc((size_t)NN * 4);
  size_t o_Xa1    = alloc((size_t)NN * 128 * 4);
  size_t o_Xb1    = alloc((size_t)NN * 128 * 4);
  size_t o_Xa2    = alloc((size_t)NN * 128 * 4);
  size_t o_Xb2    = alloc((size_t)NN * 128 * 4);
  size_t o_pooled = alloc((size_t)GG * 256 * 4);
  size_t o_gb     = alloc((size_t)2 * (GG + 1) * 4);

  int* rowptr = (int*)(ws + o_rowptr);
  int* col = (int*)(ws + o_col);
  int* counts = (int*)(ws + o_cnts);
  int* sliceptr = (int*)(ws + o_slptr);
  float* vv = (float*)(ws + o_v);
  short* whiT = (short*)(ws + o_whiT);
  short* wloT = (short*)(ws + o_wloT);
  unsigned short* hA = (unsigned short*)(ws + o_hA);
  unsigned short* hB = (unsigned short*)(ws + o_hB);
  int2* pairs = (int2*)(ws + o_hA);  // 16 MB alias over hA+hB (dead until GEMMs)
  float* sA = (float*)(ws + o_sA);
  float* sB = (float*)(ws + o_sB);
  float* Xa1 = (float*)(ws + o_Xa1);
  float* Xb1 = (float*)(ws + o_Xb1);
  float* Xa2 = (float*)(ws + o_Xa2);
  float* Xb2 = (float*)(ws + o_Xb2);
  float* pooled = (float*)(ws + o_pooled);
  int* gbA = (int*)(ws + o_gb);
  int* gbB = gbA + (GG + 1);

  v_kernel<<<8, 128, 0, stream>>>(wdst, attdst, vv);
  wcvt_kernel<<<8, 256, 0, stream>>>(wsrc, whiT, wloT);
  gbound_kernel<<<1, 192, 0, stream>>>(batchA, batchB, gbA, gbB);
  pcount_kernel<<<dim3(NCH, 4), 256, 0, stream>>>(ei0, ei1, ei2, ei3, counts);
  pscan_kernel<<<1, 256, 0, stream>>>(counts, sliceptr);
  ppart_kernel<<<dim3(NCH, 4), 256, 0, stream>>>(ei0, ei1, ei2, ei3, counts, pairs);
  pbuild_kernel<<<dim3(NSL, 4), 256, 0, stream>>>(pairs, sliceptr, rowptr, col);

  int gemm_gx = (NN + 127) / 128;
  int agg_gx = (NN + 3) / 4;

  for (int L = 0; L < 2; L++) {
    const float* X0 = (L == 0) ? xA : Xa1;
    const float* X1 = (L == 0) ? xB : Xb1;
    float* Y0 = (L == 0) ? Xa1 : Xa2;
    float* Y1 = (L == 0) ? Xb1 : Xb2;

    gemm_hs_kernel<<<dim3(gemm_gx, 1, 2), 256, 0, stream>>>(
        X0, whiT + (size_t)(L * 4 + 0) * 16384, wloT + (size_t)(L * 4 + 0) * 16384,
        attsrc + (L * 4 + 0) * 128, hA, sA,
        X1, whiT + (size_t)(L * 4 + 2) * 16384, wloT + (size_t)(L * 4 + 2) * 16384,
        attsrc + (L * 4 + 2) * 128, hB, sB);
    agg_kernel<<<agg_gx, 256, 0, stream>>>(
        X0,
        rowptr + (size_t)0 * (NN + 1), col + (size_t)0 * EE, hA, sA, vv + (L * 4 + 0) * 128, cbias + (L * 4 + 0) * 128,
        rowptr + (size_t)2 * (NN + 1), col + (size_t)2 * EE, hB, sB, vv + (L * 4 + 2) * 128, cbias + (L * 4 + 2) * 128,
        Y0);

    gemm_hs_kernel<<<dim3(gemm_gx, 1, 2), 256, 0, stream>>>(
        X0, whiT + (size_t)(L * 4 + 1) * 16384, wloT + (size_t)(L * 4 + 1) * 16384,
        attsrc + (L * 4 + 1) * 128, hA, sA,
        X1, whiT + (size_t)(L * 4 + 3) * 16384, wloT + (size_t)(L * 4 + 3) * 16384,
        attsrc + (L * 4 + 3) * 128, hB, sB);
    agg_kernel<<<agg_gx, 256, 0, stream>>>(
        X1,
        rowptr + (size_t)1 * (NN + 1), col + (size_t)1 * EE, hA, sA, vv + (L * 4 + 1) * 128, cbias + (L * 4 + 1) * 128,
        rowptr + (size_t)3 * (NN + 1), col + (size_t)3 * EE, hB, sB, vv + (L * 4 + 3) * 128, cbias + (L * 4 + 3) * 128,
        Y1);
  }

  pool2_kernel<<<dim3(GG, 2), 256, 0, stream>>>(Xa2, Xb2, gbA, gbB, pooled);
  final_kernel<<<3, 256, 0, stream>>>(pooled, wc, bc, out);
}